// Round 9
// baseline (1235.810 us; speedup 1.0000x reference)
//
#include <hip/hip_runtime.h>
#include <math.h>

#define TT 32
#define NB 32
#define DOBS 64
#define HID 512
#define HEADS 4
#define MEM 128
#define NACT 16
#define XID 3607
#define G3 1536

#define NXIJ 10      // xi j-tiles (384 cols each)
#define NXII 8       // xi i-tiles (128 rows = 4 timesteps each)

__device__ __forceinline__ float sigm(float x){ return 1.0f/(1.0f+__expf(-x)); }
__device__ __forceinline__ float splus(float x){ return fmaxf(x,0.f) + log1pf(__expf(-fabsf(x))); }

// full-wave (64) sum; xor-32 level on the VALU via v_permlane32_swap_b32 (HW-proven r2-r8)
__device__ __forceinline__ float wsum64(float s){
    s += __shfl_xor(s,1); s += __shfl_xor(s,2); s += __shfl_xor(s,4);
    s += __shfl_xor(s,8); s += __shfl_xor(s,16);
    float t = s;
    asm volatile("v_permlane32_swap_b32 %0, %1" : "+v"(s), "+v"(t));
    return s + t;
}
// sum over lane^16 and lane^32 groups (permlane swaps; HW-proven r5-r8)
__device__ __forceinline__ float rsum_hi(float v){
    float t = v;
    asm volatile("v_permlane16_swap_b32 %0, %1" : "+v"(v), "+v"(t));
    v += t;
    float t2 = v;
    asm volatile("v_permlane32_swap_b32 %0, %1" : "+v"(v), "+v"(t2));
    return v + t2;
}

// ---------------- transpose (32x32 tiles via LDS) ----------------
__global__ __launch_bounds__(256) void k_transpose(const float* __restrict__ src,
                                                   float* __restrict__ dst, int R, int C)
{
    __shared__ float tile[32][33];
    int r0 = blockIdx.x*32, c0 = blockIdx.y*32;
    int tx = threadIdx.x, ty = threadIdx.y;
    #pragma unroll
    for (int yy = 0; yy < 32; yy += 8) {
        int r = r0 + ty + yy, c = c0 + tx;
        if (r < R && c < C) tile[ty+yy][tx] = src[(size_t)r*C + c];
    }
    __syncthreads();
    #pragma unroll
    for (int yy = 0; yy < 32; yy += 8) {
        int c = c0 + ty + yy, r = r0 + tx;
        if (r < R && c < C) dst[(size_t)c*R + r] = tile[tx][ty+yy];
    }
}

// ---------------- critic head ----------------
__global__ __launch_bounds__(64) void k_val(
    const float* __restrict__ h_all, const float* __restrict__ Wc,
    const float* __restrict__ bc, float* __restrict__ out)
{
    const int row = blockIdx.x;
    const int lane = threadIdx.x;
    float acc = 0.f;
    for (int d = lane; d < HID; d += 64) acc += h_all[(size_t)row*HID + d]*Wc[d];
    for (int off = 32; off; off >>= 1) acc += __shfl_down(acc, off);
    if (lane == 0) out[(size_t)row*17 + 16] = acc + bc[0];
}

// ---------------- fused pipeline kernel ----------------
#define LPAD 132
#define SROW2 576
#define DYN_FLOATS (128*LPAD + 16*SROW2)
#define CIDX(d) ((((d)>>6)*68) + ((d)&63))
#define CIDX2(d) ((((d)>>5)*36) + ((d)&31))

__global__ __launch_bounds__(1024) void k_fused(
    const float* __restrict__ x,
    const float* __restrict__ wihT,   // [64][1536]
    const float* __restrict__ whhT,   // [512][1536]
    const float* __restrict__ b_ih,
    const float* __restrict__ b_hh,
    float* h_all,                     // [T*N][512]
    const float* __restrict__ Wf,
    const float* __restrict__ bf,
    float* xi_all,                    // [1024][3607]
    const float* __restrict__ Wa,     // [16][512]
    const float* __restrict__ ba,     // [16]
    float* __restrict__ out,          // [1024][17]
    float* hG,                        // [NB][512] h exchange (uncached atomics, proven)
    int* flagsN,                      // [NB] per-chain arrival counters
    int* gstep,                       // [1] global gru step counter
    int* xidone)                      // [NXII] xi i-tile completion counters
{
    extern __shared__ __align__(16) float dynS[];
    const int bid = blockIdx.x;
    const int tid = threadIdx.x;

    if (bid >= 32 && bid < 160) {
        // ================= GRU role: 4 blocks per chain (r3/r8-proven body) =================
        const int g = bid - 32;
        const int n = g & 31, sl = g >> 5;
        float* hS = dynS;               // 512
        float* xS = dynS + 512;         // 64
        float* pI = dynS + 576;         // [4][96][4]
        float* pH = dynS + 2112;        // [4][96][4]
        float* grS = dynS + 3648;       // 128
        float* gzS = dynS + 3776;
        float* giN = dynS + 3904;
        float* ghN = dynS + 4032;

        const int kq = tid / 96;        // valid tid<384
        const int c  = tid % 96;
        const int gg = c >> 5;
        const int r0 = gg*512 + sl*128 + (c & 31)*4;

        for (int i = tid; i < 512; i += 1024) hS[i] = 0.f;

        for (int t = 0; t < TT; ++t) {
            if (tid < 64) xS[tid] = x[((size_t)t*NB + n)*DOBS + tid];
            __syncthreads();
            if (tid < 384) {
                float4 aI = make_float4(0.f,0.f,0.f,0.f);
                float4 aH = make_float4(0.f,0.f,0.f,0.f);
                const int kx0 = kq*16;
                #pragma unroll 4
                for (int k = kx0; k < kx0+16; ++k) {
                    float xv = xS[k];
                    float4 w = *(const float4*)(wihT + (size_t)k*G3 + r0);
                    aI.x += w.x*xv; aI.y += w.y*xv; aI.z += w.z*xv; aI.w += w.w*xv;
                }
                const int kh0 = kq*128;
                #pragma unroll 4
                for (int k = kh0; k < kh0+128; ++k) {
                    float hv = hS[k];
                    float4 w = *(const float4*)(whhT + (size_t)k*G3 + r0);
                    aH.x += w.x*hv; aH.y += w.y*hv; aH.z += w.z*hv; aH.w += w.w*hv;
                }
                *(float4*)&pI[(kq*96 + c)*4] = aI;
                *(float4*)&pH[(kq*96 + c)*4] = aH;
            }
            __syncthreads();
            if (tid < 384) {
                const int g2 = tid >> 7, d = tid & 127;
                const int c2 = g2*32 + (d>>2), e = d & 3;
                float AI = 0.f, AH = 0.f;
                #pragma unroll
                for (int q = 0; q < 4; ++q) {
                    AI += pI[(q*96 + c2)*4 + e];
                    AH += pH[(q*96 + c2)*4 + e];
                }
                const int rg = g2*512 + sl*128 + d;
                AI += b_ih[rg]; AH += b_hh[rg];
                if (g2 == 0)      grS[d] = AI + AH;
                else if (g2 == 1) gzS[d] = AI + AH;
                else              { giN[d] = AI; ghN[d] = AH; }
            }
            __syncthreads();
            if (tid < 128) {
                const int D = sl*128 + tid;
                float rg = sigm(grS[tid]);
                float zg = sigm(gzS[tid]);
                float ng = tanhf(giN[tid] + rg*ghN[tid]);
                float hn = (1.f-zg)*ng + zg*hS[D];
                h_all[((size_t)t*NB + n)*HID + D] = hn;   // NORMAL cached store; wbl2'd by release below
                __hip_atomic_store(&hG[n*HID + D], hn, __ATOMIC_RELAXED, __HIP_MEMORY_SCOPE_AGENT);
            }
            __syncthreads();   // vmcnt(0): slice stores drained to L2 before release
            if (tid == 0) {
                // release: buffer_wbl2 pushes this XCD's dirty h_all lines to L3, then bump gstep
                __hip_atomic_fetch_add(gstep, 1, __ATOMIC_RELEASE, __HIP_MEMORY_SCOPE_AGENT);
                if (t+1 < TT) {
                    __hip_atomic_fetch_add(&flagsN[n], 1, __ATOMIC_RELEASE, __HIP_MEMORY_SCOPE_AGENT);
                    while (__hip_atomic_load(&flagsN[n], __ATOMIC_ACQUIRE, __HIP_MEMORY_SCOPE_AGENT) < 4*(t+1)) {
                        __builtin_amdgcn_s_sleep(4);
                    }
                }
            }
            if (t+1 < TT) {
                __syncthreads();
                for (int i = tid; i < 512; i += 1024)
                    hS[i] = __hip_atomic_load(&hG[n*HID + i], __ATOMIC_RELAXED, __HIP_MEMORY_SCOPE_AGENT);
                // loop-top __syncthreads covers hS visibility
            }
        }
        return;
    }

    if (bid >= 160) {
        // ================= XI role: 128-row x 384-col tiles (r4-proven body, cached loads) =================
        const int q2 = bid - 160;
        const int jtile = q2 % NXIJ, itile = q2 / NXIJ;
        const int it = itile*128, jt = jtile*384;
        float* As = dynS;               // [16][132]
        float* Bs = dynS + 16*132;      // [16][400]
        const int q  = tid >> 8;        // quarter 0..3 (96 cols each)
        const int t8 = tid & 255;
        const int lc = t8 & 15, lr = t8 >> 4;
        const int tx = t8 & 15, ty = t8 >> 4;
        const int i2 = tid >> 4;        // 0..63

        // wait until all 128 gru blocks passed step 4*itile+3 (relaxed spin; single acquire fence after)
        if (tid == 0) {
            while (__hip_atomic_load(gstep, __ATOMIC_RELAXED, __HIP_MEMORY_SCOPE_AGENT) < 128*(4*itile+4)) {
                __builtin_amdgcn_s_sleep(8);
            }
        }
        __syncthreads();
        __builtin_amdgcn_fence(__ATOMIC_ACQUIRE, "agent");   // buffer_inv: drop stale h_all lines

        float acc[8][6] = {};
        for (int k0 = 0; k0 < HID; k0 += 16) {
            #pragma unroll
            for (int s = 0; s < 2; ++s) {
                int i = i2*2 + s;
                float hv = h_all[(size_t)(it + i)*HID + k0 + lc];   // normal cached load
                As[lc*132 + i] = fmaxf(hv, 0.f);
            }
            #pragma unroll
            for (int s = 0; s < 6; ++s) {
                int j = lr*6 + s;
                int col = jt + q*96 + j;
                Bs[lc*400 + q*100 + j] = (col < XID) ? Wf[(size_t)col*HID + k0 + lc] : 0.f;
            }
            __syncthreads();
            #pragma unroll
            for (int k = 0; k < 16; ++k) {
                float a[8], b[6];
                #pragma unroll
                for (int u = 0; u < 8; ++u) a[u] = As[k*132 + ty*8 + u];
                #pragma unroll
                for (int v = 0; v < 6; ++v) b[v] = Bs[k*400 + q*100 + tx*6 + v];
                #pragma unroll
                for (int u = 0; u < 8; ++u)
                    #pragma unroll
                    for (int v = 0; v < 6; ++v) acc[u][v] += a[u]*b[v];
            }
            __syncthreads();
        }
        #pragma unroll
        for (int u = 0; u < 8; ++u)
            #pragma unroll
            for (int v = 0; v < 6; ++v) {
                int i = it + ty*8 + u, j = jt + q*96 + tx*6 + v;
                if (j < XID) xi_all[(size_t)i*XID + j] = acc[u][v] + bf[j];   // normal cached store
            }
        __syncthreads();   // vmcnt(0): tile stores drained to L2
        if (tid == 0)       // release: wbl2 pushes xi tile to L3, then flag
            __hip_atomic_fetch_add(&xidone[itile], 1, __ATOMIC_RELEASE, __HIP_MEMORY_SCOPE_AGENT);
        return;
    }

    // ================= MEM role (blocks 0..31): r8-proven body + group waits =================
    {
    float* Lm  = dynS;                // [128][LPAD]
    float* scr = dynS + 128*LPAD;     // [16][SROW2]

    const int n = bid;
    const int lane = tid & 63;
    const int wv = tid >> 6;          // 0..15
    const int m8 = tid >> 3;          // row 0..127
    const int q8 = tid & 7;           // col-group 0..7
    const int rp = tid >> 4;          // row-pair 0..63
    const int ch = tid & 15;          // col-chunk 0..15
    const int r0 = rp*2, r1 = r0+1;

    __shared__ __align__(16) float KrC[4*576];
    __shared__ __align__(16) float kwC[576], eC[576], vC[576];
    __shared__ __align__(16) float wrC[4*136];
    __shared__ __align__(16) float r_S[512];
    __shared__ float dotK_S[4][132], fwd_S[4][132], bwd_S[4][132];
    __shared__ float u_S[128], ww_S[128], p_S[128], aS_S[128];
    __shared__ float Mn2_S[128], dw_S[128];
    __shared__ float wred[16][6];
    __shared__ float scal_S[8];
    __shared__ float PiRaw[12];
    __shared__ float Pi_S[4][3], Br_S[4], KrN_S[4], F_S[4];
    __shared__ float ba_S[16], logit_S[16];

    float4 Mreg[16];
    #pragma unroll
    for (int i = 0; i < 16; ++i) Mreg[i] = make_float4(0.f,0.f,0.f,0.f);

    for (int i = tid; i < 128*LPAD; i += 1024) Lm[i] = 0.f;
    if (tid < 16) ba_S[tid] = ba[tid];
    if (tid < 128) { u_S[tid]=0.f; ww_S[tid]=0.f; p_S[tid]=0.f; Mn2_S[tid]=0.f; }
    if (tid < 512) wrC[(tid>>7)*136 + CIDX(tid&127)] = 0.f;

    float waR[8];
    #pragma unroll
    for (int j = 0; j < 8; ++j) waR[j] = Wa[(wv<<9) + lane + (j<<6)];

    const bool hasEx = (tid >= 1000 && tid < 1023);
    int exIdx = 0;
    if (tid >= 1000 && tid < 1004)      exIdx = 2048 + (tid - 1000);  // Br
    else if (tid == 1004)               exIdx = 2564;                 // bw
    else if (tid >= 1005 && tid < 1023) exIdx = 3589 + (tid - 1005);  // F(4),ga,gw,Pi(12)

    // wait for xi group 0 (relaxed spin + single acquire fence)
    if (tid == 0) {
        while (__hip_atomic_load(&xidone[0], __ATOMIC_RELAXED, __HIP_MEMORY_SCOPE_AGENT) < NXIJ) {
            __builtin_amdgcn_s_sleep(8);
        }
    }
    __syncthreads();   // b0: LDS init + group-0 ready
    __builtin_amdgcn_fence(__ATOMIC_ACQUIRE, "agent");

    // initial prefetch (t = 0) -- normal cached loads
    const float* xi0 = xi_all + (size_t)n*XID;
    float pKrA = xi0[tid];
    float pKrB = xi0[1024 + tid];
    float pkw = 0.f, pv = 0.f, pe = 0.f;
    if (tid < 512) { pkw = xi0[2052 + tid]; pv = xi0[3077 + tid]; }
    else           { pe  = xi0[2565 + (tid - 512)]; }
    float pex = hasEx ? xi0[exIdx] : 0.f;

    for (int t = 0; t < TT; ++t) {
        float ev2 = 0.f, evA = 0.f;

        // ---- P0: reg -> LDS with activations; norm partials; prefetch(t+1) ----
        {
            int d = tid & 511, hh = tid >> 9;
            int co = CIDX2(d);
            KrC[hh*576 + co]     = pKrA;
            KrC[(2+hh)*576 + co] = pKrB;
        }
        if (tid < 512) { int co = CIDX2(tid); kwC[co] = pkw; vC[co] = pv; }
        else { int s2 = tid - 512; eC[CIDX2(s2)] = sigm(pe); }
        if (hasEx) {
            if (tid < 1004)      Br_S[tid-1000] = splus(pex);
            else if (tid==1004)  scal_S[0] = splus(pex);
            else if (tid < 1009) F_S[tid-1005] = sigm(pex);
            else if (tid==1009)  scal_S[1] = sigm(pex);
            else if (tid==1010)  scal_S[2] = sigm(pex);
            else                 PiRaw[tid-1011] = pex;
        }
        {
            float sA = wsum64(pKrA*pKrA);
            float sB = wsum64(pKrB*pKrB);
            float sK = wsum64(pkw*pkw);
            if (lane == 0) { wred[wv][0]=sA; wred[wv][1]=sB; wred[wv][2]=sK; }
        }
        {   // prefetch next step (wait for its xi group at group boundaries)
            int tn = (t+1 < TT) ? (t+1) : t;
            if (t+1 < TT && ((t+1) & 3) == 0) {
                if (tid == 0) {
                    while (__hip_atomic_load(&xidone[(t+1)>>2], __ATOMIC_RELAXED, __HIP_MEMORY_SCOPE_AGENT) < NXIJ) {
                        __builtin_amdgcn_s_sleep(8);
                    }
                }
                __syncthreads();
                __builtin_amdgcn_fence(__ATOMIC_ACQUIRE, "agent");
            }
            const float* xin = xi_all + (size_t)(tn*NB + n)*XID;
            pKrA = xin[tid]; pKrB = xin[1024 + tid];
            if (tid < 512) { pkw = xin[2052 + tid]; pv = xin[3077 + tid]; }
            else           { pe  = xin[2565 + (tid - 512)]; }
            if (hasEx) pex = xin[exIdx];
        }
        __syncthreads();   // b1

        // ---- A: finalize norms; usage update; kw dots on OLD M ----
        if (tid < 4) {
            float s = 0.f;
            #pragma unroll
            for (int w = 0; w < 8; ++w) s += wred[(tid&1)*8 + w][tid>>1];
            KrN_S[tid] = sqrtf(s);
        } else if (tid == 4) {
            float s = 0.f;
            #pragma unroll
            for (int w = 0; w < 8; ++w) s += wred[w][2];
            scal_S[3] = sqrtf(s);
        }
        if (tid < 128) {
            int co = CIDX(tid);
            float psi = (1.f - F_S[0]*wrC[co])      * (1.f - F_S[1]*wrC[136+co])
                      * (1.f - F_S[2]*wrC[272+co])  * (1.f - F_S[3]*wrC[408+co]);
            float uu = u_S[tid], w = ww_S[tid];
            u_S[tid] = (uu + w - uu*w)*psi;
        }
        {
            const float* kwp = kwC + ch*36;
            float dw0 = 0.f, dw1 = 0.f;
            #pragma unroll
            for (int c = 0; c < 8; ++c) {
                float4 kk = *(const float4*)(kwp + 4*c);
                float4 x0 = Mreg[c], x1 = Mreg[8+c];
                dw0 += x0.x*kk.x + x0.y*kk.y + x0.z*kk.z + x0.w*kk.w;
                dw1 += x1.x*kk.x + x1.y*kk.y + x1.z*kk.z + x1.w*kk.w;
            }
            dw0 += __shfl_xor(dw0,1); dw0 += __shfl_xor(dw0,2); dw0 += __shfl_xor(dw0,4); dw0 += __shfl_xor(dw0,8);
            dw1 += __shfl_xor(dw1,1); dw1 += __shfl_xor(dw1,2); dw1 += __shfl_xor(dw1,4); dw1 += __shfl_xor(dw1,8);
            if (ch == 0) { dw_S[r0] = dw0; dw_S[r1] = dw1; }
        }
        __syncthreads();   // b2

        // ---- B: allocation via direct product-of-smaller; cw exp+sum; Pi ----
        {
            float um = u_S[m8];
            float pr = 1.f;
            #pragma unroll
            for (int jj = 0; jj < 16; ++jj) {
                int j = jj*8 + q8;
                float uj = u_S[j];
                pr *= ((uj < um) || (uj == um && j < m8)) ? uj : 1.f;
            }
            pr *= __shfl_xor(pr, 1);
            pr *= __shfl_xor(pr, 2);
            pr *= __shfl_xor(pr, 4);
            if (q8 == 0) aS_S[m8] = (1.f - um)*pr;
        }
        if (tid < 128) {
            float cwv = scal_S[0]*dw_S[tid]/(Mn2_S[tid]*scal_S[3] + 1e-8f);
            evA = __expf(cwv);
            float s = wsum64(evA);
            if (lane == 0) wred[wv][1] = s;
        } else if (tid >= 136 && tid < 140) {
            int h = tid - 136;
            float p0 = PiRaw[3*h], p1 = PiRaw[3*h+1], p2 = PiRaw[3*h+2];
            float mx = fmaxf(p0, fmaxf(p1, p2));
            float e0=__expf(p0-mx), e1=__expf(p1-mx), e2=__expf(p2-mx);
            float s = e0+e1+e2;
            Pi_S[h][0]=e0/s; Pi_S[h][1]=e1/s; Pi_S[h][2]=e2/s;
        }
        __syncthreads();   // b3

        // ---- E: write weighting ww + sum partials ----
        if (tid < 128) {
            float cwsum = wred[0][1] + wred[1][1];
            float alloc = aS_S[tid];
            float ga = scal_S[1], gw = scal_S[2];
            float w = gw*(ga*alloc + (1.f-ga)*evA/cwsum);
            ww_S[tid] = w;
            float s = wsum64(w);
            if (lane == 0) wred[wv][0] = s;
        }
        __syncthreads();   // b4

        // ---- G: precedence; M erase/write + read-key dots + new norm ----
        if (tid < 128) {
            float sww = wred[0][0] + wred[1][0];
            p_S[tid] = (1.f - sww)*p_S[tid] + ww_S[tid];
        }
        {
            const int base = ch*36;
            const float* ep  = eC + base;
            const float* vp  = vC + base;
            const float* k0p = KrC + base;
            const float* k1p = KrC + 576 + base;
            const float* k2p = KrC + 1152 + base;
            const float* k3p = KrC + 1728 + base;
            const float ww0 = ww_S[r0], ww1 = ww_S[r1];
            float nrm0=0.f, nrm1=0.f;
            float a0=0.f,a1=0.f,a2=0.f,a3=0.f;
            float b0=0.f,b1=0.f,b2=0.f,b3=0.f;
            #pragma unroll
            for (int c = 0; c < 8; ++c) {
                float4 ee = *(const float4*)(ep + 4*c);
                float4 vv = *(const float4*)(vp + 4*c);
                float4 xx  = Mreg[c];
                xx.x = xx.x*(1.f - ww0*ee.x) + ww0*vv.x;
                xx.y = xx.y*(1.f - ww0*ee.y) + ww0*vv.y;
                xx.z = xx.z*(1.f - ww0*ee.z) + ww0*vv.z;
                xx.w = xx.w*(1.f - ww0*ee.w) + ww0*vv.w;
                Mreg[c] = xx;
                nrm0 += xx.x*xx.x + xx.y*xx.y + xx.z*xx.z + xx.w*xx.w;
                float4 yy  = Mreg[8+c];
                yy.x = yy.x*(1.f - ww1*ee.x) + ww1*vv.x;
                yy.y = yy.y*(1.f - ww1*ee.y) + ww1*vv.y;
                yy.z = yy.z*(1.f - ww1*ee.z) + ww1*vv.z;
                yy.w = yy.w*(1.f - ww1*ee.w) + ww1*vv.w;
                Mreg[8+c] = yy;
                nrm1 += yy.x*yy.x + yy.y*yy.y + yy.z*yy.z + yy.w*yy.w;
                float4 k0 = *(const float4*)(k0p + 4*c);
                float4 k1 = *(const float4*)(k1p + 4*c);
                float4 k2 = *(const float4*)(k2p + 4*c);
                float4 k3 = *(const float4*)(k3p + 4*c);
                a0 += xx.x*k0.x + xx.y*k0.y + xx.z*k0.z + xx.w*k0.w;
                a1 += xx.x*k1.x + xx.y*k1.y + xx.z*k1.z + xx.w*k1.w;
                a2 += xx.x*k2.x + xx.y*k2.y + xx.z*k2.z + xx.w*k2.w;
                a3 += xx.x*k3.x + xx.y*k3.y + xx.z*k3.z + xx.w*k3.w;
                b0 += yy.x*k0.x + yy.y*k0.y + yy.z*k0.z + yy.w*k0.w;
                b1 += yy.x*k1.x + yy.y*k1.y + yy.z*k1.z + yy.w*k1.w;
                b2 += yy.x*k2.x + yy.y*k2.y + yy.z*k2.z + yy.w*k2.w;
                b3 += yy.x*k3.x + yy.y*k3.y + yy.z*k3.z + yy.w*k3.w;
            }
            #pragma unroll
            for (int mk = 1; mk < 16; mk <<= 1) {
                nrm0 += __shfl_xor(nrm0,mk); nrm1 += __shfl_xor(nrm1,mk);
                a0 += __shfl_xor(a0,mk); a1 += __shfl_xor(a1,mk);
                a2 += __shfl_xor(a2,mk); a3 += __shfl_xor(a3,mk);
                b0 += __shfl_xor(b0,mk); b1 += __shfl_xor(b1,mk);
                b2 += __shfl_xor(b2,mk); b3 += __shfl_xor(b3,mk);
            }
            if (ch < 4) {
                float dA = (ch==0)?a0:(ch==1)?a1:(ch==2)?a2:a3;
                float dB = (ch==0)?b0:(ch==1)?b1:(ch==2)?b2:b3;
                dotK_S[ch][r0] = dA;
                dotK_S[ch][r1] = dB;
            } else if (ch == 4) {
                Mn2_S[r0] = sqrtf(nrm0);
                Mn2_S[r1] = sqrtf(nrm1);
            }
        }
        __syncthreads();   // b5

        // ---- H: link matrix update + bwd partials ----
        {
            const int j2 = tid & 127, w8 = tid >> 7;
            float wwj = ww_S[j2], pj = p_S[j2];
            float b0=0.f,b1=0.f,b2=0.f,b3=0.f;
            #pragma unroll
            for (int c2 = 0; c2 < 4; ++c2) {
                const int rr0 = (w8<<4) + (c2<<2);
                const int bidx = CIDX(rr0);
                float4 wwv = *(const float4*)&ww_S[rr0];
                float4 w0v = *(const float4*)&wrC[bidx];
                float4 w1v = *(const float4*)&wrC[136+bidx];
                float4 w2v = *(const float4*)&wrC[272+bidx];
                float4 w3v = *(const float4*)&wrC[408+bidx];
                #pragma unroll
                for (int s4 = 0; s4 < 4; ++s4) {
                    int i2 = rr0 + s4;
                    float wwi = (s4==0)?wwv.x:(s4==1)?wwv.y:(s4==2)?wwv.z:wwv.w;
                    float lold = Lm[i2*LPAD + j2];
                    float ln = (1.f - wwi - wwj)*lold + wwi*pj;
                    Lm[i2*LPAD + j2] = ln;
                    b0 += ln*((s4==0)?w0v.x:(s4==1)?w0v.y:(s4==2)?w0v.z:w0v.w);
                    b1 += ln*((s4==0)?w1v.x:(s4==1)?w1v.y:(s4==2)?w1v.z:w1v.w);
                    b2 += ln*((s4==0)?w2v.x:(s4==1)?w2v.y:(s4==2)?w2v.z:w2v.w);
                    b3 += ln*((s4==0)?w3v.x:(s4==1)?w3v.y:(s4==2)?w3v.z:w3v.w);
                }
            }
            float* sp = scr + w8*SROW2 + j2;
            sp[0]=b0; sp[132]=b1; sp[264]=b2; sp[396]=b3;
        }
        __syncthreads();   // b6

        // ---- I: bwd combine; fwd; content-read exp + sum ----
        if (tid < 512) {
            int h = tid>>7, mm = tid&127;
            float s = 0.f;
            #pragma unroll
            for (int g = 0; g < 8; ++g) s += scr[g*SROW2 + h*132 + mm];
            bwd_S[h][mm] = s;
        }
        {
            const float* Lr = Lm + m8*LPAD + q8*16;
            const int wb = ((q8>>2)*68) + ((q8&3)<<4);
            float f0=0.f,f1=0.f,f2=0.f,f3=0.f;
            #pragma unroll
            for (int c = 0; c < 4; ++c) {
                float4 lv = *(const float4*)(Lr + 4*c);
                float4 w0 = *(const float4*)&wrC[wb + 4*c];
                float4 w1 = *(const float4*)&wrC[136 + wb + 4*c];
                float4 w2 = *(const float4*)&wrC[272 + wb + 4*c];
                float4 w3 = *(const float4*)&wrC[408 + wb + 4*c];
                f0 += lv.x*w0.x + lv.y*w0.y + lv.z*w0.z + lv.w*w0.w;
                f1 += lv.x*w1.x + lv.y*w1.y + lv.z*w1.z + lv.w*w1.w;
                f2 += lv.x*w2.x + lv.y*w2.y + lv.z*w2.z + lv.w*w2.w;
                f3 += lv.x*w3.x + lv.y*w3.y + lv.z*w3.z + lv.w*w3.w;
            }
            f0 += __shfl_xor(f0,1); f0 += __shfl_xor(f0,2); f0 += __shfl_xor(f0,4);
            f1 += __shfl_xor(f1,1); f1 += __shfl_xor(f1,2); f1 += __shfl_xor(f1,4);
            f2 += __shfl_xor(f2,1); f2 += __shfl_xor(f2,2); f2 += __shfl_xor(f2,4);
            f3 += __shfl_xor(f3,1); f3 += __shfl_xor(f3,2); f3 += __shfl_xor(f3,4);
            if (q8 < 4) fwd_S[q8][m8] = (q8==0) ? f0 : ((q8==1) ? f1 : ((q8==2) ? f2 : f3));
        }
        if (tid < 512) {
            int h = tid>>7, mm = tid&127;
            float scv = Br_S[h]*dotK_S[h][mm]/(Mn2_S[mm]*KrN_S[h] + 1e-8f);
            ev2 = __expf(scv);
            float s = wsum64(ev2);
            if (lane == 0) wred[wv][1] = s;
        }
        __syncthreads();   // b7

        // ---- K: new read weights ----
        if (tid < 512) {
            int h = tid>>7, mm = tid&127;
            float hsum = wred[2*h][1] + wred[2*h+1][1];
            float cr = ev2/hsum;
            wrC[h*136 + CIDX(mm)] = Pi_S[h][0]*bwd_S[h][mm] + Pi_S[h][1]*cr + Pi_S[h][2]*fwd_S[h][mm];
        }
        __syncthreads();   // b8

        // ---- M: read vectors (2-row combine in VALU; permlane row-tree) ----
        {
            const int co0 = CIDX(r0), co1 = CIDX(r1);
            float s0 = wrC[co0] + wrC[136+co0] + wrC[272+co0] + wrC[408+co0];
            float s1 = wrC[co1] + wrC[136+co1] + wrC[272+co1] + wrC[408+co1];
            float* sp = scr + wv*SROW2 + ch*36;
            #pragma unroll
            for (int c = 0; c < 8; ++c) {
                float4 xx = Mreg[c], yy = Mreg[8+c];
                float px = rsum_hi(s0*xx.x + s1*yy.x);
                float py = rsum_hi(s0*xx.y + s1*yy.y);
                float pz = rsum_hi(s0*xx.z + s1*yy.z);
                float pw = rsum_hi(s0*xx.w + s1*yy.w);
                if (lane < 16) *(float4*)(sp + 4*c) = make_float4(px,py,pz,pw);
            }
        }
        __syncthreads();   // b9

        // ---- N: combine r over 16 waves (float4, 2 waves) ----
        if (tid < 128) {
            const int off = CIDX2(tid<<2);
            float4 r = make_float4(0.f,0.f,0.f,0.f);
            #pragma unroll
            for (int w = 0; w < 16; ++w) {
                float4 v = *(const float4*)&scr[w*SROW2 + off];
                r.x += v.x; r.y += v.y; r.z += v.z; r.w += v.w;
            }
            *(float4*)&r_S[tid<<2] = r;
        }
        __syncthreads();   // b10

        // ---- O: actor logits (one wave per logit, Wa in registers) ----
        {
            float acc = 0.f;
            #pragma unroll
            for (int j = 0; j < 8; ++j) acc += waR[j]*r_S[lane + (j<<6)];
            acc = wsum64(acc);
            if (lane == 0) logit_S[wv] = acc + ba_S[wv];
        }
        __syncthreads();   // b11

        // ---- P: actor softmax + output (16 lanes) ----
        if (tid < 16) {
            float lg = logit_S[tid];
            float mx = lg;
            mx = fmaxf(mx, __shfl_xor(mx,1)); mx = fmaxf(mx, __shfl_xor(mx,2));
            mx = fmaxf(mx, __shfl_xor(mx,4)); mx = fmaxf(mx, __shfl_xor(mx,8));
            float ex2 = __expf(lg - mx);
            float s = ex2;
            s += __shfl_xor(s,1); s += __shfl_xor(s,2);
            s += __shfl_xor(s,4); s += __shfl_xor(s,8);
            out[(size_t)(t*NB + n)*17 + tid] = ex2/s;
        }
    }
    }
}

// ---------------- host launch ----------------
extern "C" void kernel_launch(void* const* d_in, const int* in_sizes, int n_in,
                              void* d_out, int out_size, void* d_ws, size_t ws_size,
                              hipStream_t stream) {
    const float* inp  = (const float*)d_in[0];
    const float* w_ih = (const float*)d_in[1];
    const float* w_hh = (const float*)d_in[2];
    const float* b_ih = (const float*)d_in[3];
    const float* b_hh = (const float*)d_in[4];
    const float* Wf   = (const float*)d_in[5];
    const float* bf   = (const float*)d_in[6];
    const float* Wa   = (const float*)d_in[7];
    const float* ba   = (const float*)d_in[8];
    const float* Wc   = (const float*)d_in[9];
    const float* bc   = (const float*)d_in[10];
    float* out = (float*)d_out;

    float* ws = (float*)d_ws;
    float* wihT   = ws;                       // 64*1536
    float* whhT   = ws + 98304;               // 512*1536
    float* h_all  = ws + 884736;              // 1024*512
    float* xi_all = ws + 1409024;             // 1024*3607
    float* hG     = ws + 5102592;             // 32*512 h exchange
    int*   flagsN = (int*)(ws + 5119008);     // 32 chain counters
    int*   gstep  = flagsN + 32;              // 1 global step counter
    int*   xidone = gstep + 1;                // 8 xi i-tile counters

    static int dynset = 0;
    if (!dynset) {
        hipFuncSetAttribute(reinterpret_cast<const void*>(k_fused),
                            hipFuncAttributeMaxDynamicSharedMemorySize,
                            DYN_FLOATS*4);
        dynset = 1;
    }

    hipMemsetAsync(flagsN, 0, 64*sizeof(int), stream);

    dim3 tb(32, 8);
    k_transpose<<<dim3(48, 2),  tb, 0, stream>>>(w_ih, wihT, G3, DOBS);
    k_transpose<<<dim3(48, 16), tb, 0, stream>>>(w_hh, whhT, G3, HID);
    k_fused<<<32 + 128 + NXII*NXIJ, 1024, DYN_FLOATS*4, stream>>>(
        inp, wihT, whhT, b_ih, b_hh, h_all, Wf, bf, xi_all, Wa, ba, out,
        hG, flagsN, gstep, xidone);
    k_val<<<TT*NB, 64, 0, stream>>>(h_all, Wc, bc, out);
}

// Round 10
// 1206.210 us; speedup vs baseline: 1.0245x; 1.0245x over previous
//
#include <hip/hip_runtime.h>
#include <math.h>

#define TT 32
#define NB 32
#define DOBS 64
#define HID 512
#define HEADS 4
#define MEM 128
#define NACT 16
#define XID 3607
#define G3 1536

__device__ __forceinline__ float sigm(float x){ return 1.0f/(1.0f+__expf(-x)); }
__device__ __forceinline__ float splus(float x){ return fmaxf(x,0.f) + log1pf(__expf(-fabsf(x))); }
__device__ __forceinline__ float bf2f(unsigned short u){ return __uint_as_float(((unsigned)u)<<16); }

// full-wave (64) sum; xor-32 level on the VALU via v_permlane32_swap_b32 (HW-proven r2-r8)
__device__ __forceinline__ float wsum64(float s){
    s += __shfl_xor(s,1); s += __shfl_xor(s,2); s += __shfl_xor(s,4);
    s += __shfl_xor(s,8); s += __shfl_xor(s,16);
    float t = s;
    asm volatile("v_permlane32_swap_b32 %0, %1" : "+v"(s), "+v"(t));
    return s + t;
}
// sum over lane^16 and lane^32 groups (permlane swaps; HW-proven r5-r8)
__device__ __forceinline__ float rsum_hi(float v){
    float t = v;
    asm volatile("v_permlane16_swap_b32 %0, %1" : "+v"(v), "+v"(t));
    v += t;
    float t2 = v;
    asm volatile("v_permlane32_swap_b32 %0, %1" : "+v"(v), "+v"(t2));
    return v + t2;
}

// ---------------- transpose + fp32->bf16 convert (32x32 tiles via LDS) ----------------
__global__ __launch_bounds__(256) void k_transpose_bf16(const float* __restrict__ src,
                                                        unsigned short* __restrict__ dst, int R, int C)
{
    __shared__ float tile[32][33];
    int r0 = blockIdx.x*32, c0 = blockIdx.y*32;
    int tx = threadIdx.x, ty = threadIdx.y;
    #pragma unroll
    for (int yy = 0; yy < 32; yy += 8) {
        int r = r0 + ty + yy, c = c0 + tx;
        if (r < R && c < C) tile[ty+yy][tx] = src[(size_t)r*C + c];
    }
    __syncthreads();
    #pragma unroll
    for (int yy = 0; yy < 32; yy += 8) {
        int c = c0 + ty + yy, r = r0 + tx;
        if (r < R && c < C) {
            unsigned u = __float_as_uint(tile[tx][ty+yy]);
            u += 0x7fffu + ((u >> 16) & 1u);           // RNE to bf16
            dst[(size_t)c*R + r] = (unsigned short)(u >> 16);
        }
    }
}

// ---------------- GRU: 4 blocks per chain, bf16 weights, per-step rendezvous (protocol r3/r8) ----------------
__global__ __launch_bounds__(384) void k_gru(
    const float* __restrict__ x,
    const unsigned short* __restrict__ wihT,   // [64][1536] bf16
    const unsigned short* __restrict__ whhT,   // [512][1536] bf16
    const float* __restrict__ b_ih,
    const float* __restrict__ b_hh,
    float* __restrict__ h_all,        // [T*N][512]
    float* hG,                        // [NB][512] exchange buffer
    int* flags)                       // [NB] monotone arrival counters
{
    const int n   = blockIdx.x & 31;
    const int s   = blockIdx.x >> 5;        // h-slice 0..3
    const int tid = threadIdx.x;
    const int kq  = tid / 96;               // k-quarter 0..3
    const int c   = tid % 96;               // chunk 0..95 (4 rows each)
    const int g   = c >> 5;                 // gate 0..2 (r,z,n)
    const int r0  = g*512 + s*128 + (c & 31)*4;  // global gate-row base (x4)

    __shared__ float hS[512];
    __shared__ float xS[64];
    __shared__ float4 pI[4][96];
    __shared__ float4 pH[4][96];
    __shared__ float grS[128], gzS[128], giN[128], ghN[128];

    for (int i = tid; i < 512; i += 384) hS[i] = 0.f;

    for (int t = 0; t < TT; ++t) {
        if (tid < 64) xS[tid] = x[((size_t)t*NB + n)*DOBS + tid];
        __syncthreads();   // hS + xS ready
        {
            float4 aI = make_float4(0.f,0.f,0.f,0.f);
            float4 aH = make_float4(0.f,0.f,0.f,0.f);
            const int kx0 = kq*16;
            #pragma unroll 4
            for (int k = kx0; k < kx0+16; ++k) {
                float xv = xS[k];
                ushort4 w = *(const ushort4*)(wihT + (size_t)k*G3 + r0);
                aI.x += bf2f(w.x)*xv; aI.y += bf2f(w.y)*xv;
                aI.z += bf2f(w.z)*xv; aI.w += bf2f(w.w)*xv;
            }
            const int kh0 = kq*128;
            #pragma unroll 4
            for (int k = kh0; k < kh0+128; ++k) {
                float hv = hS[k];
                ushort4 w = *(const ushort4*)(whhT + (size_t)k*G3 + r0);
                aH.x += bf2f(w.x)*hv; aH.y += bf2f(w.y)*hv;
                aH.z += bf2f(w.z)*hv; aH.w += bf2f(w.w)*hv;
            }
            pI[kq][c] = aI; pH[kq][c] = aH;
        }
        __syncthreads();
        // reduce over k-quarters + bias + gate staging: thread -> (gate g2, dim d)
        {
            const int g2 = tid >> 7, d = tid & 127;
            const int c2 = g2*32 + (d>>2), e = d & 3;
            float AI = 0.f, AH = 0.f;
            #pragma unroll
            for (int q = 0; q < 4; ++q) {
                float4 vi = pI[q][c2], vh = pH[q][c2];
                AI += (e==0)?vi.x:(e==1)?vi.y:(e==2)?vi.z:vi.w;
                AH += (e==0)?vh.x:(e==1)?vh.y:(e==2)?vh.z:vh.w;
            }
            const int rg = g2*512 + s*128 + d;
            AI += b_ih[rg]; AH += b_hh[rg];
            if (g2 == 0)      grS[d] = AI + AH;
            else if (g2 == 1) gzS[d] = AI + AH;
            else              { giN[d] = AI; ghN[d] = AH; }
        }
        __syncthreads();
        if (tid < 128) {
            const int D = s*128 + tid;
            float rg = sigm(grS[tid]);
            float zg = sigm(gzS[tid]);
            float ng = tanhf(giN[tid] + rg*ghN[tid]);
            float hn = (1.f-zg)*ng + zg*hS[D];
            h_all[((size_t)t*NB + n)*HID + D] = hn;
            __hip_atomic_store(&hG[n*HID + D], hn, __ATOMIC_RELAXED, __HIP_MEMORY_SCOPE_AGENT);
        }
        __syncthreads();   // all slice stores drained (vmcnt 0) before arrival
        if (t+1 < TT) {
            if (tid == 0) {
                __hip_atomic_fetch_add(&flags[n], 1, __ATOMIC_RELEASE, __HIP_MEMORY_SCOPE_AGENT);
                while (__hip_atomic_load(&flags[n], __ATOMIC_ACQUIRE, __HIP_MEMORY_SCOPE_AGENT) < 4*(t+1)) {
                    __builtin_amdgcn_s_sleep(4);
                }
            }
            __syncthreads();
            for (int i = tid; i < 512; i += 384)
                hS[i] = __hip_atomic_load(&hG[n*HID + i], __ATOMIC_RELAXED, __HIP_MEMORY_SCOPE_AGENT);
            // loop-top __syncthreads covers hS visibility
        }
    }
}

// ---------------- xi = relu(h_all) @ Wf^T + bf  (128x64 tiles, 8x4 acc, float4 LDS reads) ----------------
__global__ __launch_bounds__(256) void k_xi(
    const float* __restrict__ h_all,
    const float* __restrict__ Wf,
    const float* __restrict__ bf,
    float* __restrict__ xi_all)
{
    __shared__ float As[16][132];
    __shared__ float Bs[16][68];
    const int jt = blockIdx.x * 64;
    const int it = blockIdx.y * 128;
    const int tid = threadIdx.x;
    const int lc = tid & 15, lr = tid >> 4;
    const int tx = tid & 15, ty = tid >> 4;
    float acc[8][4] = {};

    for (int k0 = 0; k0 < HID; k0 += 16) {
        #pragma unroll
        for (int s = 0; s < 8; ++s) {
            int i = lr*8 + s;
            As[lc][i] = fmaxf(h_all[(size_t)(it + i)*HID + k0 + lc], 0.f);
        }
        #pragma unroll
        for (int s = 0; s < 4; ++s) {
            int j = lr*4 + s;
            Bs[lc][j] = (jt + j < XID) ? Wf[(size_t)(jt + j)*HID + k0 + lc] : 0.f;
        }
        __syncthreads();
        #pragma unroll
        for (int k = 0; k < 16; ++k) {
            float4 a0 = *(const float4*)&As[k][ty*8];
            float4 a1 = *(const float4*)&As[k][ty*8+4];
            float4 bv = *(const float4*)&Bs[k][tx*4];
            float a[8] = {a0.x,a0.y,a0.z,a0.w,a1.x,a1.y,a1.z,a1.w};
            float b[4] = {bv.x,bv.y,bv.z,bv.w};
            #pragma unroll
            for (int u = 0; u < 8; ++u)
                #pragma unroll
                for (int v = 0; v < 4; ++v) acc[u][v] += a[u]*b[v];
        }
        __syncthreads();
    }
    #pragma unroll
    for (int u = 0; u < 8; ++u)
        #pragma unroll
        for (int v = 0; v < 4; ++v) {
            int i = it + ty*8 + u, j = jt + tx*4 + v;
            if (j < XID) xi_all[(size_t)i*XID + j] = acc[u][v] + bf[j];
        }
}

// ---------------- critic head ----------------
__global__ __launch_bounds__(64) void k_val(
    const float* __restrict__ h_all, const float* __restrict__ Wc,
    const float* __restrict__ bc, float* __restrict__ out)
{
    const int row = blockIdx.x;
    const int lane = threadIdx.x;
    float acc = 0.f;
    for (int d = lane; d < HID; d += 64) acc += h_all[(size_t)row*HID + d]*Wc[d];
    for (int off = 32; off; off >>= 1) acc += __shfl_down(acc, off);
    if (lane == 0) out[(size_t)row*17 + 16] = acc + bc[0];
}

// ---------------- memory recurrence: 1024 threads; M = 2 rows x 32 cols / thread ----------------
#define LPAD 132
#define SROW2 576
#define DYN_FLOATS (128*LPAD + 16*SROW2)
// wr layout (2 chunks of 64, pad 68)
#define CIDX(d) ((((d)>>6)*68) + ((d)&63))
// operand layout: 16 chunks of 32 cols, pad to 36 (bank-spread, <=2-way on b128)
#define CIDX2(d) ((((d)>>5)*36) + ((d)&31))

__global__ __launch_bounds__(1024) void k_mem(
    const float* __restrict__ xi_all, // [1024][3607]
    const float* __restrict__ Wa,     // [16][512]
    const float* __restrict__ ba,     // [16]
    float* __restrict__ out)          // [1024][17]
{
    extern __shared__ __align__(16) float dynS[];
    float* Lm  = dynS;                // [128][LPAD]
    float* scr = dynS + 128*LPAD;     // [16][SROW2]

    const int n = blockIdx.x;
    const int tid = threadIdx.x;
    const int lane = tid & 63;
    const int wv = tid >> 6;          // 0..15
    const int m8 = tid >> 3;          // row 0..127  (alloc/fwd phases)
    const int q8 = tid & 7;           // col-group 0..7 (fwd phase)
    const int rp = tid >> 4;          // row-pair 0..63 (M phases)
    const int ch = tid & 15;          // col-chunk 0..15 (32 cols each)
    const int r0 = rp*2, r1 = r0+1;   // owned M rows

    __shared__ __align__(16) float KrC[4*576];            // [head][16 chunks][36]
    __shared__ __align__(16) float kwC[576], eC[576], vC[576];
    __shared__ __align__(16) float wrC[4*136];            // [head][2 chunks][68]
    __shared__ __align__(16) float r_S[512];
    __shared__ float dotK_S[4][132], fwd_S[4][132], bwd_S[4][132];
    __shared__ float u_S[128], ww_S[128], p_S[128], aS_S[128];
    __shared__ float Mn2_S[128], dw_S[128];
    __shared__ float wred[16][6];
    __shared__ float scal_S[8];                 // 0=bw 1=ga 2=gw 3=kwn
    __shared__ float PiRaw[12];
    __shared__ float Pi_S[4][3], Br_S[4], KrN_S[4], F_S[4];
    __shared__ float ba_S[16], logit_S[16];

    // M rows r0,r1; cols ch*32 + 4c + j. Mreg[c] = row r0, Mreg[8+c] = row r1.
    float4 Mreg[16];
    #pragma unroll
    for (int i = 0; i < 16; ++i) Mreg[i] = make_float4(0.f,0.f,0.f,0.f);

    for (int i = tid; i < 128*LPAD; i += 1024) Lm[i] = 0.f;
    if (tid < 16) ba_S[tid] = ba[tid];
    if (tid < 128) { u_S[tid]=0.f; ww_S[tid]=0.f; p_S[tid]=0.f; Mn2_S[tid]=0.f; }
    if (tid < 512) wrC[(tid>>7)*136 + CIDX(tid&127)] = 0.f;

    // Wa resident in registers: wave wv owns logit wv; lane holds d = lane+64j
    float waR[8];
    #pragma unroll
    for (int j = 0; j < 8; ++j) waR[j] = Wa[(wv<<9) + lane + (j<<6)];

    // extra-scalar mapping (23 scalars on threads 1000..1022)
    const bool hasEx = (tid >= 1000 && tid < 1023);
    int exIdx = 0;
    if (tid >= 1000 && tid < 1004)      exIdx = 2048 + (tid - 1000);  // Br
    else if (tid == 1004)               exIdx = 2564;                 // bw
    else if (tid >= 1005 && tid < 1023) exIdx = 3589 + (tid - 1005);  // F(4),ga,gw,Pi(12)

    // initial prefetch (t = 0)
    const float* xi0 = xi_all + (size_t)n*XID;
    float pKrA = xi0[tid];
    float pKrB = xi0[1024 + tid];
    float pkw = 0.f, pv = 0.f, pe = 0.f;
    if (tid < 512) { pkw = xi0[2052 + tid]; pv = xi0[3077 + tid]; }
    else           { pe  = xi0[2565 + (tid - 512)]; }
    float pex = hasEx ? xi0[exIdx] : 0.f;
    __syncthreads();   // b0: LDS init done

    for (int t = 0; t < TT; ++t) {
        float ev2 = 0.f, evA = 0.f;

        // ---- P0: reg -> LDS with activations; norm partials; prefetch(t+1) ----
        {
            int d = tid & 511, hh = tid >> 9;
            int co = CIDX2(d);
            KrC[hh*576 + co]     = pKrA;
            KrC[(2+hh)*576 + co] = pKrB;
        }
        if (tid < 512) { int co = CIDX2(tid); kwC[co] = pkw; vC[co] = pv; }
        else { int s2 = tid - 512; eC[CIDX2(s2)] = sigm(pe); }
        if (hasEx) {
            if (tid < 1004)      Br_S[tid-1000] = splus(pex);
            else if (tid==1004)  scal_S[0] = splus(pex);
            else if (tid < 1009) F_S[tid-1005] = sigm(pex);
            else if (tid==1009)  scal_S[1] = sigm(pex);
            else if (tid==1010)  scal_S[2] = sigm(pex);
            else                 PiRaw[tid-1011] = pex;
        }
        {
            float sA = wsum64(pKrA*pKrA);
            float sB = wsum64(pKrB*pKrB);
            float sK = wsum64(pkw*pkw);
            if (lane == 0) { wred[wv][0]=sA; wred[wv][1]=sB; wred[wv][2]=sK; }
        }
        {   // prefetch next step
            int tn = (t+1 < TT) ? (t+1) : t;
            const float* xin = xi_all + (size_t)(tn*NB + n)*XID;
            pKrA = xin[tid]; pKrB = xin[1024 + tid];
            if (tid < 512) { pkw = xin[2052 + tid]; pv = xin[3077 + tid]; }
            else           { pe  = xin[2565 + (tid - 512)]; }
            if (hasEx) pex = xin[exIdx];
        }
        __syncthreads();   // b1

        // ---- A: finalize norms; usage update; kw dots on OLD M ----
        if (tid < 4) {
            float s = 0.f;
            #pragma unroll
            for (int w = 0; w < 8; ++w) s += wred[(tid&1)*8 + w][tid>>1];
            KrN_S[tid] = sqrtf(s);
        } else if (tid == 4) {
            float s = 0.f;
            #pragma unroll
            for (int w = 0; w < 8; ++w) s += wred[w][2];
            scal_S[3] = sqrtf(s);
        }
        if (tid < 128) {
            int co = CIDX(tid);
            float psi = (1.f - F_S[0]*wrC[co])      * (1.f - F_S[1]*wrC[136+co])
                      * (1.f - F_S[2]*wrC[272+co])  * (1.f - F_S[3]*wrC[408+co]);
            float uu = u_S[tid], w = ww_S[tid];
            u_S[tid] = (uu + w - uu*w)*psi;
        }
        {
            const float* kwp = kwC + ch*36;
            float dw0 = 0.f, dw1 = 0.f;
            #pragma unroll
            for (int c = 0; c < 8; ++c) {
                float4 kk = *(const float4*)(kwp + 4*c);
                float4 x0 = Mreg[c], x1 = Mreg[8+c];
                dw0 += x0.x*kk.x + x0.y*kk.y + x0.z*kk.z + x0.w*kk.w;
                dw1 += x1.x*kk.x + x1.y*kk.y + x1.z*kk.z + x1.w*kk.w;
            }
            dw0 += __shfl_xor(dw0,1); dw0 += __shfl_xor(dw0,2); dw0 += __shfl_xor(dw0,4); dw0 += __shfl_xor(dw0,8);
            dw1 += __shfl_xor(dw1,1); dw1 += __shfl_xor(dw1,2); dw1 += __shfl_xor(dw1,4); dw1 += __shfl_xor(dw1,8);
            if (ch == 0) { dw_S[r0] = dw0; dw_S[r1] = dw1; }
        }
        __syncthreads();   // b2

        // ---- B: allocation via direct product-of-smaller (shfl_xor mult); cw exp+sum; Pi ----
        {
            float um = u_S[m8];
            float pr = 1.f;
            #pragma unroll
            for (int jj = 0; jj < 16; ++jj) {
                int j = jj*8 + q8;
                float uj = u_S[j];
                pr *= ((uj < um) || (uj == um && j < m8)) ? uj : 1.f;
            }
            pr *= __shfl_xor(pr, 1);
            pr *= __shfl_xor(pr, 2);
            pr *= __shfl_xor(pr, 4);
            if (q8 == 0) aS_S[m8] = (1.f - um)*pr;
        }
        if (tid < 128) {
            float cwv = scal_S[0]*dw_S[tid]/(Mn2_S[tid]*scal_S[3] + 1e-8f);
            evA = __expf(cwv);
            float s = wsum64(evA);
            if (lane == 0) wred[wv][1] = s;
        } else if (tid >= 136 && tid < 140) {
            int h = tid - 136;
            float p0 = PiRaw[3*h], p1 = PiRaw[3*h+1], p2 = PiRaw[3*h+2];
            float mx = fmaxf(p0, fmaxf(p1, p2));
            float e0=__expf(p0-mx), e1=__expf(p1-mx), e2=__expf(p2-mx);
            float s = e0+e1+e2;
            Pi_S[h][0]=e0/s; Pi_S[h][1]=e1/s; Pi_S[h][2]=e2/s;
        }
        __syncthreads();   // b3

        // ---- E: write weighting ww + sum partials ----
        if (tid < 128) {
            float cwsum = wred[0][1] + wred[1][1];
            float alloc = aS_S[tid];
            float ga = scal_S[1], gw = scal_S[2];
            float w = gw*(ga*alloc + (1.f-ga)*evA/cwsum);
            ww_S[tid] = w;
            float s = wsum64(w);
            if (lane == 0) wred[wv][0] = s;
        }
        __syncthreads();   // b4

        // ---- G: precedence; M erase/write + read-key dots + new norm (2 rows/thread) ----
        if (tid < 128) {
            float sww = wred[0][0] + wred[1][0];
            p_S[tid] = (1.f - sww)*p_S[tid] + ww_S[tid];
        }
        {
            const int base = ch*36;
            const float* ep  = eC + base;
            const float* vp  = vC + base;
            const float* k0p = KrC + base;
            const float* k1p = KrC + 576 + base;
            const float* k2p = KrC + 1152 + base;
            const float* k3p = KrC + 1728 + base;
            const float ww0 = ww_S[r0], ww1 = ww_S[r1];
            float nrm0=0.f, nrm1=0.f;
            float a0=0.f,a1=0.f,a2=0.f,a3=0.f;   // row r0 dots
            float b0=0.f,b1=0.f,b2=0.f,b3=0.f;   // row r1 dots
            #pragma unroll
            for (int c = 0; c < 8; ++c) {
                float4 ee = *(const float4*)(ep + 4*c);
                float4 vv = *(const float4*)(vp + 4*c);
                float4 x  = Mreg[c];
                x.x = x.x*(1.f - ww0*ee.x) + ww0*vv.x;
                x.y = x.y*(1.f - ww0*ee.y) + ww0*vv.y;
                x.z = x.z*(1.f - ww0*ee.z) + ww0*vv.z;
                x.w = x.w*(1.f - ww0*ee.w) + ww0*vv.w;
                Mreg[c] = x;
                nrm0 += x.x*x.x + x.y*x.y + x.z*x.z + x.w*x.w;
                float4 y  = Mreg[8+c];
                y.x = y.x*(1.f - ww1*ee.x) + ww1*vv.x;
                y.y = y.y*(1.f - ww1*ee.y) + ww1*vv.y;
                y.z = y.z*(1.f - ww1*ee.z) + ww1*vv.z;
                y.w = y.w*(1.f - ww1*ee.w) + ww1*vv.w;
                Mreg[8+c] = y;
                nrm1 += y.x*y.x + y.y*y.y + y.z*y.z + y.w*y.w;
                float4 k0 = *(const float4*)(k0p + 4*c);
                float4 k1 = *(const float4*)(k1p + 4*c);
                float4 k2 = *(const float4*)(k2p + 4*c);
                float4 k3 = *(const float4*)(k3p + 4*c);
                a0 += x.x*k0.x + x.y*k0.y + x.z*k0.z + x.w*k0.w;
                a1 += x.x*k1.x + x.y*k1.y + x.z*k1.z + x.w*k1.w;
                a2 += x.x*k2.x + x.y*k2.y + x.z*k2.z + x.w*k2.w;
                a3 += x.x*k3.x + x.y*k3.y + x.z*k3.z + x.w*k3.w;
                b0 += y.x*k0.x + y.y*k0.y + y.z*k0.z + y.w*k0.w;
                b1 += y.x*k1.x + y.y*k1.y + y.z*k1.z + y.w*k1.w;
                b2 += y.x*k2.x + y.y*k2.y + y.z*k2.z + y.w*k2.w;
                b3 += y.x*k3.x + y.y*k3.y + y.z*k3.z + y.w*k3.w;
            }
            #pragma unroll
            for (int mk = 1; mk < 16; mk <<= 1) {
                nrm0 += __shfl_xor(nrm0,mk); nrm1 += __shfl_xor(nrm1,mk);
                a0 += __shfl_xor(a0,mk); a1 += __shfl_xor(a1,mk);
                a2 += __shfl_xor(a2,mk); a3 += __shfl_xor(a3,mk);
                b0 += __shfl_xor(b0,mk); b1 += __shfl_xor(b1,mk);
                b2 += __shfl_xor(b2,mk); b3 += __shfl_xor(b3,mk);
            }
            if (ch < 4) {
                float dA = (ch==0)?a0:(ch==1)?a1:(ch==2)?a2:a3;
                float dB = (ch==0)?b0:(ch==1)?b1:(ch==2)?b2:b3;
                dotK_S[ch][r0] = dA;
                dotK_S[ch][r1] = dB;
            } else if (ch == 4) {
                Mn2_S[r0] = sqrtf(nrm0);
                Mn2_S[r1] = sqrtf(nrm1);
            }
        }
        __syncthreads();   // b5

        // ---- H: link matrix update + bwd partials ----
        {
            const int j2 = tid & 127, w8 = tid >> 7;
            float wwj = ww_S[j2], pj = p_S[j2];
            float b0=0.f,b1=0.f,b2=0.f,b3=0.f;
            #pragma unroll
            for (int c2 = 0; c2 < 4; ++c2) {
                const int rr0 = (w8<<4) + (c2<<2);
                const int bidx = CIDX(rr0);
                float4 wwv = *(const float4*)&ww_S[rr0];
                float4 w0v = *(const float4*)&wrC[bidx];
                float4 w1v = *(const float4*)&wrC[136+bidx];
                float4 w2v = *(const float4*)&wrC[272+bidx];
                float4 w3v = *(const float4*)&wrC[408+bidx];
                #pragma unroll
                for (int s4 = 0; s4 < 4; ++s4) {
                    int i2 = rr0 + s4;
                    float wwi = (s4==0)?wwv.x:(s4==1)?wwv.y:(s4==2)?wwv.z:wwv.w;
                    float lold = Lm[i2*LPAD + j2];
                    float ln = (1.f - wwi - wwj)*lold + wwi*pj;
                    Lm[i2*LPAD + j2] = ln;
                    b0 += ln*((s4==0)?w0v.x:(s4==1)?w0v.y:(s4==2)?w0v.z:w0v.w);
                    b1 += ln*((s4==0)?w1v.x:(s4==1)?w1v.y:(s4==2)?w1v.z:w1v.w);
                    b2 += ln*((s4==0)?w2v.x:(s4==1)?w2v.y:(s4==2)?w2v.z:w2v.w);
                    b3 += ln*((s4==0)?w3v.x:(s4==1)?w3v.y:(s4==2)?w3v.z:w3v.w);
                }
            }
            float* sp = scr + w8*SROW2 + j2;
            sp[0]=b0; sp[132]=b1; sp[264]=b2; sp[396]=b3;
        }
        __syncthreads();   // b6

        // ---- I: bwd combine; fwd; content-read exp + sum ----
        if (tid < 512) {
            int h = tid>>7, mm = tid&127;
            float s = 0.f;
            #pragma unroll
            for (int g = 0; g < 8; ++g) s += scr[g*SROW2 + h*132 + mm];
            bwd_S[h][mm] = s;
        }
        {
            const float* Lr = Lm + m8*LPAD + q8*16;
            const int wb = ((q8>>2)*68) + ((q8&3)<<4);
            float f0=0.f,f1=0.f,f2=0.f,f3=0.f;
            #pragma unroll
            for (int c = 0; c < 4; ++c) {
                float4 lv = *(const float4*)(Lr + 4*c);
                float4 w0 = *(const float4*)&wrC[wb + 4*c];
                float4 w1 = *(const float4*)&wrC[136 + wb + 4*c];
                float4 w2 = *(const float4*)&wrC[272 + wb + 4*c];
                float4 w3 = *(const float4*)&wrC[408 + wb + 4*c];
                f0 += lv.x*w0.x + lv.y*w0.y + lv.z*w0.z + lv.w*w0.w;
                f1 += lv.x*w1.x + lv.y*w1.y + lv.z*w1.z + lv.w*w1.w;
                f2 += lv.x*w2.x + lv.y*w2.y + lv.z*w2.z + lv.w*w2.w;
                f3 += lv.x*w3.x + lv.y*w3.y + lv.z*w3.z + lv.w*w3.w;
            }
            f0 += __shfl_xor(f0,1); f0 += __shfl_xor(f0,2); f0 += __shfl_xor(f0,4);
            f1 += __shfl_xor(f1,1); f1 += __shfl_xor(f1,2); f1 += __shfl_xor(f1,4);
            f2 += __shfl_xor(f2,1); f2 += __shfl_xor(f2,2); f2 += __shfl_xor(f2,4);
            f3 += __shfl_xor(f3,1); f3 += __shfl_xor(f3,2); f3 += __shfl_xor(f3,4);
            if (q8 < 4) fwd_S[q8][m8] = (q8==0) ? f0 : ((q8==1) ? f1 : ((q8==2) ? f2 : f3));
        }
        if (tid < 512) {
            int h = tid>>7, mm = tid&127;
            float scv = Br_S[h]*dotK_S[h][mm]/(Mn2_S[mm]*KrN_S[h] + 1e-8f);
            ev2 = __expf(scv);
            float s = wsum64(ev2);
            if (lane == 0) wred[wv][1] = s;
        }
        __syncthreads();   // b7

        // ---- K: new read weights ----
        if (tid < 512) {
            int h = tid>>7, mm = tid&127;
            float hsum = wred[2*h][1] + wred[2*h+1][1];
            float cr = ev2/hsum;
            wrC[h*136 + CIDX(mm)] = Pi_S[h][0]*bwd_S[h][mm] + Pi_S[h][1]*cr + Pi_S[h][2]*fwd_S[h][mm];
        }
        __syncthreads();   // b8

        // ---- M: read vectors (2-row combine in VALU; permlane row-tree; 0 DS shuffles) ----
        {
            const int co0 = CIDX(r0), co1 = CIDX(r1);
            float s0 = wrC[co0] + wrC[136+co0] + wrC[272+co0] + wrC[408+co0];
            float s1 = wrC[co1] + wrC[136+co1] + wrC[272+co1] + wrC[408+co1];
            float* sp = scr + wv*SROW2 + ch*36;
            #pragma unroll
            for (int c = 0; c < 8; ++c) {
                float4 x = Mreg[c], y = Mreg[8+c];
                float px = rsum_hi(s0*x.x + s1*y.x);
                float py = rsum_hi(s0*x.y + s1*y.y);
                float pz = rsum_hi(s0*x.z + s1*y.z);
                float pw = rsum_hi(s0*x.w + s1*y.w);
                if (lane < 16) *(float4*)(sp + 4*c) = make_float4(px,py,pz,pw);
            }
        }
        __syncthreads();   // b9

        // ---- N: combine r over 16 waves (float4, 2 waves) ----
        if (tid < 128) {
            const int off = CIDX2(tid<<2);
            float4 r = make_float4(0.f,0.f,0.f,0.f);
            #pragma unroll
            for (int w = 0; w < 16; ++w) {
                float4 v = *(const float4*)&scr[w*SROW2 + off];
                r.x += v.x; r.y += v.y; r.z += v.z; r.w += v.w;
            }
            *(float4*)&r_S[tid<<2] = r;
        }
        __syncthreads();   // b10

        // ---- O: actor logits (one wave per logit, Wa in registers) ----
        {
            float acc = 0.f;
            #pragma unroll
            for (int j = 0; j < 8; ++j) acc += waR[j]*r_S[lane + (j<<6)];
            acc = wsum64(acc);
            if (lane == 0) logit_S[wv] = acc + ba_S[wv];
        }
        __syncthreads();   // b11

        // ---- P: actor softmax + output (16 lanes) ----
        if (tid < 16) {
            float lg = logit_S[tid];
            float mx = lg;
            mx = fmaxf(mx, __shfl_xor(mx,1)); mx = fmaxf(mx, __shfl_xor(mx,2));
            mx = fmaxf(mx, __shfl_xor(mx,4)); mx = fmaxf(mx, __shfl_xor(mx,8));
            float ex2 = __expf(lg - mx);
            float s = ex2;
            s += __shfl_xor(s,1); s += __shfl_xor(s,2);
            s += __shfl_xor(s,4); s += __shfl_xor(s,8);
            out[(size_t)(t*NB + n)*17 + tid] = ex2/s;
        }
    }
}

// ---------------- host launch ----------------
extern "C" void kernel_launch(void* const* d_in, const int* in_sizes, int n_in,
                              void* d_out, int out_size, void* d_ws, size_t ws_size,
                              hipStream_t stream) {
    const float* inp  = (const float*)d_in[0];
    const float* w_ih = (const float*)d_in[1];
    const float* w_hh = (const float*)d_in[2];
    const float* b_ih = (const float*)d_in[3];
    const float* b_hh = (const float*)d_in[4];
    const float* Wf   = (const float*)d_in[5];
    const float* bf   = (const float*)d_in[6];
    const float* Wa   = (const float*)d_in[7];
    const float* ba   = (const float*)d_in[8];
    const float* Wc   = (const float*)d_in[9];
    const float* bc   = (const float*)d_in[10];
    float* out = (float*)d_out;

    float* ws = (float*)d_ws;
    unsigned short* wihT16 = (unsigned short*)ws;             // 64*1536 bf16
    unsigned short* whhT16 = (unsigned short*)(ws + 98304);   // 512*1536 bf16
    float* h_all  = ws + 884736;              // 1024*512
    float* xi_all = ws + 1409024;             // 1024*3607
    float* hG     = ws + 5102592;             // 32*512 h exchange
    int*   flags  = (int*)(ws + 5119008);     // 32 counters

    static int dynset = 0;
    if (!dynset) {
        hipFuncSetAttribute(reinterpret_cast<const void*>(k_mem),
                            hipFuncAttributeMaxDynamicSharedMemorySize,
                            DYN_FLOATS*4);
        dynset = 1;
    }

    hipMemsetAsync(flags, 0, NB*sizeof(int), stream);

    dim3 tb(32, 8);
    k_transpose_bf16<<<dim3(48, 2),  tb, 0, stream>>>(w_ih, wihT16, G3, DOBS);
    k_transpose_bf16<<<dim3(48, 16), tb, 0, stream>>>(w_hh, whhT16, G3, HID);
    k_gru<<<NB*4, 384, 0, stream>>>(inp, wihT16, whhT16, b_ih, b_hh, h_all, hG, flags);
    k_xi<<<dim3(57, 8), 256, 0, stream>>>(h_all, Wf, bf, xi_all);
    k_val<<<TT*NB, 64, 0, stream>>>(h_all, Wc, bc, out);
    k_mem<<<NB, 1024, DYN_FLOATS*4, stream>>>(xi_all, Wa, ba, out);
}

// Round 11
// 1165.754 us; speedup vs baseline: 1.0601x; 1.0347x over previous
//
#include <hip/hip_runtime.h>
#include <math.h>

#define TT 32
#define NB 32
#define DOBS 64
#define HID 512
#define HEADS 4
#define MEM 128
#define NACT 16
#define XID 3607
#define G3 1536

__device__ __forceinline__ float sigm(float x){ return 1.0f/(1.0f+__expf(-x)); }
__device__ __forceinline__ float splus(float x){ return fmaxf(x,0.f) + log1pf(__expf(-fabsf(x))); }

// full-wave (64) sum; xor-32 level on the VALU via v_permlane32_swap_b32 (HW-proven r2-r10)
__device__ __forceinline__ float wsum64(float s){
    s += __shfl_xor(s,1); s += __shfl_xor(s,2); s += __shfl_xor(s,4);
    s += __shfl_xor(s,8); s += __shfl_xor(s,16);
    float t = s;
    asm volatile("v_permlane32_swap_b32 %0, %1" : "+v"(s), "+v"(t));
    return s + t;
}
// sum over lane^16 and lane^32 groups (permlane swaps; HW-proven r5-r10)
__device__ __forceinline__ float rsum_hi(float v){
    float t = v;
    asm volatile("v_permlane16_swap_b32 %0, %1" : "+v"(v), "+v"(t));
    v += t;
    float t2 = v;
    asm volatile("v_permlane32_swap_b32 %0, %1" : "+v"(v), "+v"(t2));
    return v + t2;
}

// ---------------- transpose (32x32 tiles via LDS) ----------------
__global__ __launch_bounds__(256) void k_transpose(const float* __restrict__ src,
                                                   float* __restrict__ dst, int R, int C)
{
    __shared__ float tile[32][33];
    int r0 = blockIdx.x*32, c0 = blockIdx.y*32;
    int tx = threadIdx.x, ty = threadIdx.y;
    #pragma unroll
    for (int yy = 0; yy < 32; yy += 8) {
        int r = r0 + ty + yy, c = c0 + tx;
        if (r < R && c < C) tile[ty+yy][tx] = src[(size_t)r*C + c];
    }
    __syncthreads();
    #pragma unroll
    for (int yy = 0; yy < 32; yy += 8) {
        int c = c0 + ty + yy, r = r0 + tx;
        if (r < R && c < C) dst[(size_t)c*R + r] = tile[tx][ty+yy];
    }
}

// ---------------- GRU: 4 blocks per chain; RELAXED spin (no per-poll buffer_inv) ----------------
__global__ __launch_bounds__(384) void k_gru(
    const float* __restrict__ x,
    const float* __restrict__ wihT,   // [64][1536]
    const float* __restrict__ whhT,   // [512][1536]
    const float* __restrict__ b_ih,
    const float* __restrict__ b_hh,
    float* __restrict__ h_all,        // [T*N][512]
    float* hG,                        // [NB][512] exchange buffer (uncached atomics)
    int* flags)                       // [NB] monotone arrival counters
{
    const int n   = blockIdx.x & 31;
    const int s   = blockIdx.x >> 5;        // h-slice 0..3
    const int tid = threadIdx.x;
    const int kq  = tid / 96;               // k-quarter 0..3
    const int c   = tid % 96;               // chunk 0..95 (4 rows each)
    const int g   = c >> 5;                 // gate 0..2 (r,z,n)
    const int r0  = g*512 + s*128 + (c & 31)*4;  // global gate-row base (float4)

    __shared__ float hS[512];
    __shared__ float xS[64];
    __shared__ float4 pI[4][96];
    __shared__ float4 pH[4][96];
    __shared__ float grS[128], gzS[128], giN[128], ghN[128];

    for (int i = tid; i < 512; i += 384) hS[i] = 0.f;

    for (int t = 0; t < TT; ++t) {
        if (tid < 64) xS[tid] = x[((size_t)t*NB + n)*DOBS + tid];
        __syncthreads();   // hS + xS ready
        {
            float4 aI = make_float4(0.f,0.f,0.f,0.f);
            float4 aH = make_float4(0.f,0.f,0.f,0.f);
            const int kx0 = kq*16;
            #pragma unroll 4
            for (int k = kx0; k < kx0+16; ++k) {
                float xv = xS[k];
                float4 w = *(const float4*)(wihT + (size_t)k*G3 + r0);
                aI.x += w.x*xv; aI.y += w.y*xv; aI.z += w.z*xv; aI.w += w.w*xv;
            }
            const int kh0 = kq*128;
            #pragma unroll 4
            for (int k = kh0; k < kh0+128; ++k) {
                float hv = hS[k];
                float4 w = *(const float4*)(whhT + (size_t)k*G3 + r0);
                aH.x += w.x*hv; aH.y += w.y*hv; aH.z += w.z*hv; aH.w += w.w*hv;
            }
            pI[kq][c] = aI; pH[kq][c] = aH;
        }
        __syncthreads();
        // reduce over k-quarters + bias + gate staging: thread -> (gate g2, dim d)
        {
            const int g2 = tid >> 7, d = tid & 127;
            const int c2 = g2*32 + (d>>2), e = d & 3;
            float AI = 0.f, AH = 0.f;
            #pragma unroll
            for (int q = 0; q < 4; ++q) {
                float4 vi = pI[q][c2], vh = pH[q][c2];
                AI += (e==0)?vi.x:(e==1)?vi.y:(e==2)?vi.z:vi.w;
                AH += (e==0)?vh.x:(e==1)?vh.y:(e==2)?vh.z:vh.w;
            }
            const int rg = g2*512 + s*128 + d;
            AI += b_ih[rg]; AH += b_hh[rg];
            if (g2 == 0)      grS[d] = AI + AH;
            else if (g2 == 1) gzS[d] = AI + AH;
            else              { giN[d] = AI; ghN[d] = AH; }
        }
        __syncthreads();
        if (tid < 128) {
            const int D = s*128 + tid;
            float rg = sigm(grS[tid]);
            float zg = sigm(gzS[tid]);
            float ng = tanhf(giN[tid] + rg*ghN[tid]);
            float hn = (1.f-zg)*ng + zg*hS[D];
            h_all[((size_t)t*NB + n)*HID + D] = hn;
            __hip_atomic_store(&hG[n*HID + D], hn, __ATOMIC_RELAXED, __HIP_MEMORY_SCOPE_AGENT);
        }
        __syncthreads();   // all slice stores drained (vmcnt 0) before arrival
        if (t+1 < TT) {
            if (tid == 0) {
                // release: orders the (uncached) hG stores before the flag bump
                __hip_atomic_fetch_add(&flags[n], 1, __ATOMIC_RELEASE, __HIP_MEMORY_SCOPE_AGENT);
                // RELAXED poll: hG is uncached, so no acquire (buffer_inv) is needed --
                // keeps whhT resident in this XCD's L2 across steps
                while (__hip_atomic_load(&flags[n], __ATOMIC_RELAXED, __HIP_MEMORY_SCOPE_AGENT) < 4*(t+1)) {
                    __builtin_amdgcn_s_sleep(4);
                }
            }
            __syncthreads();
            for (int i = tid; i < 512; i += 384)
                hS[i] = __hip_atomic_load(&hG[n*HID + i], __ATOMIC_RELAXED, __HIP_MEMORY_SCOPE_AGENT);
            // loop-top __syncthreads covers hS visibility
        }
    }
}

// ---------------- xi = relu(h_all) @ Wf^T + bf  (128x64 tiles, 8x4 acc, float4 LDS reads) ----------------
__global__ __launch_bounds__(256) void k_xi(
    const float* __restrict__ h_all,
    const float* __restrict__ Wf,
    const float* __restrict__ bf,
    float* __restrict__ xi_all)
{
    __shared__ float As[16][132];
    __shared__ float Bs[16][68];
    const int jt = blockIdx.x * 64;
    const int it = blockIdx.y * 128;
    const int tid = threadIdx.x;
    const int lc = tid & 15, lr = tid >> 4;
    const int tx = tid & 15, ty = tid >> 4;
    float acc[8][4] = {};

    for (int k0 = 0; k0 < HID; k0 += 16) {
        #pragma unroll
        for (int s = 0; s < 8; ++s) {
            int i = lr*8 + s;
            As[lc][i] = fmaxf(h_all[(size_t)(it + i)*HID + k0 + lc], 0.f);
        }
        #pragma unroll
        for (int s = 0; s < 4; ++s) {
            int j = lr*4 + s;
            Bs[lc][j] = (jt + j < XID) ? Wf[(size_t)(jt + j)*HID + k0 + lc] : 0.f;
        }
        __syncthreads();
        #pragma unroll
        for (int k = 0; k < 16; ++k) {
            float4 a0 = *(const float4*)&As[k][ty*8];
            float4 a1 = *(const float4*)&As[k][ty*8+4];
            float4 bv = *(const float4*)&Bs[k][tx*4];
            float a[8] = {a0.x,a0.y,a0.z,a0.w,a1.x,a1.y,a1.z,a1.w};
            float b[4] = {bv.x,bv.y,bv.z,bv.w};
            #pragma unroll
            for (int u = 0; u < 8; ++u)
                #pragma unroll
                for (int v = 0; v < 4; ++v) acc[u][v] += a[u]*b[v];
        }
        __syncthreads();
    }
    #pragma unroll
    for (int u = 0; u < 8; ++u)
        #pragma unroll
        for (int v = 0; v < 4; ++v) {
            int i = it + ty*8 + u, j = jt + tx*4 + v;
            if (j < XID) xi_all[(size_t)i*XID + j] = acc[u][v] + bf[j];
        }
}

// ---------------- critic head ----------------
__global__ __launch_bounds__(64) void k_val(
    const float* __restrict__ h_all, const float* __restrict__ Wc,
    const float* __restrict__ bc, float* __restrict__ out)
{
    const int row = blockIdx.x;
    const int lane = threadIdx.x;
    float acc = 0.f;
    for (int d = lane; d < HID; d += 64) acc += h_all[(size_t)row*HID + d]*Wc[d];
    for (int off = 32; off; off >>= 1) acc += __shfl_down(acc, off);
    if (lane == 0) out[(size_t)row*17 + 16] = acc + bc[0];
}

// ---------------- memory recurrence: 1024 threads; M = 2 rows x 32 cols / thread ----------------
#define LPAD 132
#define SROW2 576
#define DYN_FLOATS (128*LPAD + 16*SROW2)
// wr layout (2 chunks of 64, pad 68)
#define CIDX(d) ((((d)>>6)*68) + ((d)&63))
// operand layout: 16 chunks of 32 cols, pad to 36 (bank-spread, <=2-way on b128)
#define CIDX2(d) ((((d)>>5)*36) + ((d)&31))

__global__ __launch_bounds__(1024) void k_mem(
    const float* __restrict__ xi_all, // [1024][3607]
    const float* __restrict__ Wa,     // [16][512]
    const float* __restrict__ ba,     // [16]
    float* __restrict__ out)          // [1024][17]
{
    extern __shared__ __align__(16) float dynS[];
    float* Lm  = dynS;                // [128][LPAD]
    float* scr = dynS + 128*LPAD;     // [16][SROW2]

    const int n = blockIdx.x;
    const int tid = threadIdx.x;
    const int lane = tid & 63;
    const int wv = tid >> 6;          // 0..15
    const int m8 = tid >> 3;          // row 0..127  (alloc/fwd phases)
    const int q8 = tid & 7;           // col-group 0..7 (fwd phase)
    const int rp = tid >> 4;          // row-pair 0..63 (M phases)
    const int ch = tid & 15;          // col-chunk 0..15 (32 cols each)
    const int r0 = rp*2, r1 = r0+1;   // owned M rows

    __shared__ __align__(16) float KrC[4*576];            // [head][16 chunks][36]
    __shared__ __align__(16) float kwC[576], eC[576], vC[576];
    __shared__ __align__(16) float wrC[4*136];            // [head][2 chunks][68]
    __shared__ __align__(16) float r_S[512];
    __shared__ float dotK_S[4][132], fwd_S[4][132], bwd_S[4][132];
    __shared__ float u_S[128], ww_S[128], p_S[128], aS_S[128], cw_S[128];
    __shared__ float Mn2_S[128], dw_S[128];
    __shared__ float wred[16][6];
    __shared__ float scal_S[8];                 // 0=bw 1=ga 2=gw 3=kwn 4=prod(u)
    __shared__ float PiRaw[12];
    __shared__ float Pi_S[4][3], Br_S[4], KrN_S[4], F_S[4];
    __shared__ float ba_S[16], logit_S[16];

    // M rows r0,r1; cols ch*32 + 4c + j. Mreg[c] = row r0, Mreg[8+c] = row r1.
    float4 Mreg[16];
    #pragma unroll
    for (int i = 0; i < 16; ++i) Mreg[i] = make_float4(0.f,0.f,0.f,0.f);

    for (int i = tid; i < 128*LPAD; i += 1024) Lm[i] = 0.f;
    if (tid < 16) ba_S[tid] = ba[tid];
    if (tid < 128) { u_S[tid]=0.f; ww_S[tid]=0.f; p_S[tid]=0.f; Mn2_S[tid]=0.f; }
    if (tid < 512) wrC[(tid>>7)*136 + CIDX(tid&127)] = 0.f;

    // Wa resident in registers: wave wv owns logit wv; lane holds d = lane+64j
    float waR[8];
    #pragma unroll
    for (int j = 0; j < 8; ++j) waR[j] = Wa[(wv<<9) + lane + (j<<6)];

    // extra-scalar mapping (23 scalars on threads 1000..1022)
    const bool hasEx = (tid >= 1000 && tid < 1023);
    int exIdx = 0;
    if (tid >= 1000 && tid < 1004)      exIdx = 2048 + (tid - 1000);  // Br
    else if (tid == 1004)               exIdx = 2564;                 // bw
    else if (tid >= 1005 && tid < 1023) exIdx = 3589 + (tid - 1005);  // F(4),ga,gw,Pi(12)

    // initial prefetch (t = 0)
    const float* xi0 = xi_all + (size_t)n*XID;
    float pKrA = xi0[tid];
    float pKrB = xi0[1024 + tid];
    float pkw = 0.f, pv = 0.f, pe = 0.f;
    if (tid < 512) { pkw = xi0[2052 + tid]; pv = xi0[3077 + tid]; }
    else           { pe  = xi0[2565 + (tid - 512)]; }
    float pex = hasEx ? xi0[exIdx] : 0.f;
    __syncthreads();   // b0: LDS init done

    for (int t = 0; t < TT; ++t) {
        float ev2 = 0.f;

        // ---- P0: reg -> LDS with activations; norm partials; prefetch(t+1) ----
        {
            int d = tid & 511, hh = tid >> 9;
            int co = CIDX2(d);
            KrC[hh*576 + co]     = pKrA;
            KrC[(2+hh)*576 + co] = pKrB;
        }
        if (tid < 512) { int co = CIDX2(tid); kwC[co] = pkw; vC[co] = pv; }
        else { int s2 = tid - 512; eC[CIDX2(s2)] = sigm(pe); }
        if (hasEx) {
            if (tid < 1004)      Br_S[tid-1000] = splus(pex);
            else if (tid==1004)  scal_S[0] = splus(pex);
            else if (tid < 1009) F_S[tid-1005] = sigm(pex);
            else if (tid==1009)  scal_S[1] = sigm(pex);
            else if (tid==1010)  scal_S[2] = sigm(pex);
            else                 PiRaw[tid-1011] = pex;
        }
        {
            float sA = wsum64(pKrA*pKrA);
            float sB = wsum64(pKrB*pKrB);
            float sK = wsum64(pkw*pkw);
            if (lane == 0) { wred[wv][0]=sA; wred[wv][1]=sB; wred[wv][2]=sK; }
        }
        {   // prefetch next step
            int tn = (t+1 < TT) ? (t+1) : t;
            const float* xin = xi_all + (size_t)(tn*NB + n)*XID;
            pKrA = xin[tid]; pKrB = xin[1024 + tid];
            if (tid < 512) { pkw = xin[2052 + tid]; pv = xin[3077 + tid]; }
            else           { pe  = xin[2565 + (tid - 512)]; }
            if (hasEx) pex = xin[exIdx];
        }
        __syncthreads();   // b1

        // ---- A: finalize norms; usage update; kw dots on OLD M ----
        if (tid < 4) {
            float s = 0.f;
            #pragma unroll
            for (int w = 0; w < 8; ++w) s += wred[(tid&1)*8 + w][tid>>1];
            KrN_S[tid] = sqrtf(s);
        } else if (tid == 4) {
            float s = 0.f;
            #pragma unroll
            for (int w = 0; w < 8; ++w) s += wred[w][2];
            scal_S[3] = sqrtf(s);
        }
        if (tid < 128) {
            int co = CIDX(tid);
            float psi = (1.f - F_S[0]*wrC[co])      * (1.f - F_S[1]*wrC[136+co])
                      * (1.f - F_S[2]*wrC[272+co])  * (1.f - F_S[3]*wrC[408+co]);
            float uu = u_S[tid], w = ww_S[tid];
            u_S[tid] = (uu + w - uu*w)*psi;
        }
        {
            const float* kwp = kwC + ch*36;
            float dw0 = 0.f, dw1 = 0.f;
            #pragma unroll
            for (int c = 0; c < 8; ++c) {
                float4 kk = *(const float4*)(kwp + 4*c);
                float4 x0 = Mreg[c], x1 = Mreg[8+c];
                dw0 += x0.x*kk.x + x0.y*kk.y + x0.z*kk.z + x0.w*kk.w;
                dw1 += x1.x*kk.x + x1.y*kk.y + x1.z*kk.z + x1.w*kk.w;
            }
            dw0 += __shfl_xor(dw0,1); dw0 += __shfl_xor(dw0,2); dw0 += __shfl_xor(dw0,4); dw0 += __shfl_xor(dw0,8);
            dw1 += __shfl_xor(dw1,1); dw1 += __shfl_xor(dw1,2); dw1 += __shfl_xor(dw1,4); dw1 += __shfl_xor(dw1,8);
            if (ch == 0) { dw_S[r0] = dw0; dw_S[r1] = dw1; }
        }
        __syncthreads();   // b2

        // ---- B: allocation (product-of-smaller) + full u-product; cw exp+sum -> cw_S; Pi ----
        {
            float um = u_S[m8];
            float pr = 1.f, prAll = 1.f;
            #pragma unroll
            for (int jj = 0; jj < 16; ++jj) {
                int j = jj*8 + q8;
                float uj = u_S[j];
                pr *= ((uj < um) || (uj == um && j < m8)) ? uj : 1.f;
                prAll *= uj;
            }
            pr *= __shfl_xor(pr, 1);
            pr *= __shfl_xor(pr, 2);
            pr *= __shfl_xor(pr, 4);
            prAll *= __shfl_xor(prAll, 1);
            prAll *= __shfl_xor(prAll, 2);
            prAll *= __shfl_xor(prAll, 4);
            if (q8 == 0) aS_S[m8] = (1.f - um)*pr;
            if (tid == 0) scal_S[4] = prAll;     // prod of all 128 u's
        }
        if (tid < 128) {
            float cwv = scal_S[0]*dw_S[tid]/(Mn2_S[tid]*scal_S[3] + 1e-8f);
            float ev = __expf(cwv);
            cw_S[tid] = ev;
            float s = wsum64(ev);
            if (lane == 0) wred[wv][1] = s;
        } else if (tid >= 136 && tid < 140) {
            int h = tid - 136;
            float p0 = PiRaw[3*h], p1 = PiRaw[3*h+1], p2 = PiRaw[3*h+2];
            float mx = fmaxf(p0, fmaxf(p1, p2));
            float e0=__expf(p0-mx), e1=__expf(p1-mx), e2=__expf(p2-mx);
            float s = e0+e1+e2;
            Pi_S[h][0]=e0/s; Pi_S[h][1]=e1/s; Pi_S[h][2]=e2/s;
        }
        __syncthreads();   // b3

        // ---- G: ww per-thread (analytic sww via 1-prod(u)); precedence; M update + dots + norm ----
        {
            const float cwinv = 1.f/(wred[0][1] + wred[1][1]);
            const float ga = scal_S[1], gw = scal_S[2];
            if (tid < 128) {
                float sww = gw*(ga*(1.f - scal_S[4]) + (1.f - ga));   // sum(alloc) = 1 - prod(u)
                float w = gw*(ga*aS_S[tid] + (1.f-ga)*cw_S[tid]*cwinv);
                ww_S[tid] = w;                                        // for H + next-step A
                p_S[tid] = (1.f - sww)*p_S[tid] + w;
            }
            const float ww0 = gw*(ga*aS_S[r0] + (1.f-ga)*cw_S[r0]*cwinv);
            const float ww1 = gw*(ga*aS_S[r1] + (1.f-ga)*cw_S[r1]*cwinv);
            const int base = ch*36;
            const float* ep  = eC + base;
            const float* vp  = vC + base;
            const float* k0p = KrC + base;
            const float* k1p = KrC + 576 + base;
            const float* k2p = KrC + 1152 + base;
            const float* k3p = KrC + 1728 + base;
            float nrm0=0.f, nrm1=0.f;
            float a0=0.f,a1=0.f,a2=0.f,a3=0.f;   // row r0 dots
            float b0=0.f,b1=0.f,b2=0.f,b3=0.f;   // row r1 dots
            #pragma unroll
            for (int c = 0; c < 8; ++c) {
                float4 ee = *(const float4*)(ep + 4*c);
                float4 vv = *(const float4*)(vp + 4*c);
                float4 x  = Mreg[c];
                x.x = x.x*(1.f - ww0*ee.x) + ww0*vv.x;
                x.y = x.y*(1.f - ww0*ee.y) + ww0*vv.y;
                x.z = x.z*(1.f - ww0*ee.z) + ww0*vv.z;
                x.w = x.w*(1.f - ww0*ee.w) + ww0*vv.w;
                Mreg[c] = x;
                nrm0 += x.x*x.x + x.y*x.y + x.z*x.z + x.w*x.w;
                float4 y  = Mreg[8+c];
                y.x = y.x*(1.f - ww1*ee.x) + ww1*vv.x;
                y.y = y.y*(1.f - ww1*ee.y) + ww1*vv.y;
                y.z = y.z*(1.f - ww1*ee.z) + ww1*vv.z;
                y.w = y.w*(1.f - ww1*ee.w) + ww1*vv.w;
                Mreg[8+c] = y;
                nrm1 += y.x*y.x + y.y*y.y + y.z*y.z + y.w*y.w;
                float4 k0 = *(const float4*)(k0p + 4*c);
                float4 k1 = *(const float4*)(k1p + 4*c);
                float4 k2 = *(const float4*)(k2p + 4*c);
                float4 k3 = *(const float4*)(k3p + 4*c);
                a0 += x.x*k0.x + x.y*k0.y + x.z*k0.z + x.w*k0.w;
                a1 += x.x*k1.x + x.y*k1.y + x.z*k1.z + x.w*k1.w;
                a2 += x.x*k2.x + x.y*k2.y + x.z*k2.z + x.w*k2.w;
                a3 += x.x*k3.x + x.y*k3.y + x.z*k3.z + x.w*k3.w;
                b0 += y.x*k0.x + y.y*k0.y + y.z*k0.z + y.w*k0.w;
                b1 += y.x*k1.x + y.y*k1.y + y.z*k1.z + y.w*k1.w;
                b2 += y.x*k2.x + y.y*k2.y + y.z*k2.z + y.w*k2.w;
                b3 += y.x*k3.x + y.y*k3.y + y.z*k3.z + y.w*k3.w;
            }
            #pragma unroll
            for (int mk = 1; mk < 16; mk <<= 1) {
                nrm0 += __shfl_xor(nrm0,mk); nrm1 += __shfl_xor(nrm1,mk);
                a0 += __shfl_xor(a0,mk); a1 += __shfl_xor(a1,mk);
                a2 += __shfl_xor(a2,mk); a3 += __shfl_xor(a3,mk);
                b0 += __shfl_xor(b0,mk); b1 += __shfl_xor(b1,mk);
                b2 += __shfl_xor(b2,mk); b3 += __shfl_xor(b3,mk);
            }
            if (ch < 4) {
                float dA = (ch==0)?a0:(ch==1)?a1:(ch==2)?a2:a3;
                float dB = (ch==0)?b0:(ch==1)?b1:(ch==2)?b2:b3;
                dotK_S[ch][r0] = dA;
                dotK_S[ch][r1] = dB;
            } else if (ch == 4) {
                Mn2_S[r0] = sqrtf(nrm0);
                Mn2_S[r1] = sqrtf(nrm1);
            }
        }
        __syncthreads();   // b4

        // ---- H: link matrix update + bwd partials ----
        {
            const int j2 = tid & 127, w8 = tid >> 7;
            float wwj = ww_S[j2], pj = p_S[j2];
            float b0=0.f,b1=0.f,b2=0.f,b3=0.f;
            #pragma unroll
            for (int c2 = 0; c2 < 4; ++c2) {
                const int rr0 = (w8<<4) + (c2<<2);
                const int bidx = CIDX(rr0);
                float4 wwv = *(const float4*)&ww_S[rr0];
                float4 w0v = *(const float4*)&wrC[bidx];
                float4 w1v = *(const float4*)&wrC[136+bidx];
                float4 w2v = *(const float4*)&wrC[272+bidx];
                float4 w3v = *(const float4*)&wrC[408+bidx];
                #pragma unroll
                for (int s4 = 0; s4 < 4; ++s4) {
                    int i2 = rr0 + s4;
                    float wwi = (s4==0)?wwv.x:(s4==1)?wwv.y:(s4==2)?wwv.z:wwv.w;
                    float lold = Lm[i2*LPAD + j2];
                    float ln = (1.f - wwi - wwj)*lold + wwi*pj;
                    Lm[i2*LPAD + j2] = ln;
                    b0 += ln*((s4==0)?w0v.x:(s4==1)?w0v.y:(s4==2)?w0v.z:w0v.w);
                    b1 += ln*((s4==0)?w1v.x:(s4==1)?w1v.y:(s4==2)?w1v.z:w1v.w);
                    b2 += ln*((s4==0)?w2v.x:(s4==1)?w2v.y:(s4==2)?w2v.z:w2v.w);
                    b3 += ln*((s4==0)?w3v.x:(s4==1)?w3v.y:(s4==2)?w3v.z:w3v.w);
                }
            }
            float* sp = scr + w8*SROW2 + j2;
            sp[0]=b0; sp[132]=b1; sp[264]=b2; sp[396]=b3;
        }
        __syncthreads();   // b5

        // ---- I: bwd combine; fwd; content-read exp + sum ----
        if (tid < 512) {
            int h = tid>>7, mm = tid&127;
            float s = 0.f;
            #pragma unroll
            for (int g = 0; g < 8; ++g) s += scr[g*SROW2 + h*132 + mm];
            bwd_S[h][mm] = s;
        }
        {
            const float* Lr = Lm + m8*LPAD + q8*16;
            const int wb = ((q8>>2)*68) + ((q8&3)<<4);
            float f0=0.f,f1=0.f,f2=0.f,f3=0.f;
            #pragma unroll
            for (int c = 0; c < 4; ++c) {
                float4 lv = *(const float4*)(Lr + 4*c);
                float4 w0 = *(const float4*)&wrC[wb + 4*c];
                float4 w1 = *(const float4*)&wrC[136 + wb + 4*c];
                float4 w2 = *(const float4*)&wrC[272 + wb + 4*c];
                float4 w3 = *(const float4*)&wrC[408 + wb + 4*c];
                f0 += lv.x*w0.x + lv.y*w0.y + lv.z*w0.z + lv.w*w0.w;
                f1 += lv.x*w1.x + lv.y*w1.y + lv.z*w1.z + lv.w*w1.w;
                f2 += lv.x*w2.x + lv.y*w2.y + lv.z*w2.z + lv.w*w2.w;
                f3 += lv.x*w3.x + lv.y*w3.y + lv.z*w3.z + lv.w*w3.w;
            }
            f0 += __shfl_xor(f0,1); f0 += __shfl_xor(f0,2); f0 += __shfl_xor(f0,4);
            f1 += __shfl_xor(f1,1); f1 += __shfl_xor(f1,2); f1 += __shfl_xor(f1,4);
            f2 += __shfl_xor(f2,1); f2 += __shfl_xor(f2,2); f2 += __shfl_xor(f2,4);
            f3 += __shfl_xor(f3,1); f3 += __shfl_xor(f3,2); f3 += __shfl_xor(f3,4);
            if (q8 < 4) fwd_S[q8][m8] = (q8==0) ? f0 : ((q8==1) ? f1 : ((q8==2) ? f2 : f3));
        }
        if (tid < 512) {
            int h = tid>>7, mm = tid&127;
            float scv = Br_S[h]*dotK_S[h][mm]/(Mn2_S[mm]*KrN_S[h] + 1e-8f);
            ev2 = __expf(scv);
            float s = wsum64(ev2);
            if (lane == 0) wred[wv][1] = s;
        }
        __syncthreads();   // b6

        // ---- K: new read weights ----
        if (tid < 512) {
            int h = tid>>7, mm = tid&127;
            float hsum = wred[2*h][1] + wred[2*h+1][1];
            float cr = ev2/hsum;
            wrC[h*136 + CIDX(mm)] = Pi_S[h][0]*bwd_S[h][mm] + Pi_S[h][1]*cr + Pi_S[h][2]*fwd_S[h][mm];
        }
        __syncthreads();   // b7

        // ---- M: read vectors (2-row combine in VALU; permlane row-tree; 0 DS shuffles) ----
        {
            const int co0 = CIDX(r0), co1 = CIDX(r1);
            float s0 = wrC[co0] + wrC[136+co0] + wrC[272+co0] + wrC[408+co0];
            float s1 = wrC[co1] + wrC[136+co1] + wrC[272+co1] + wrC[408+co1];
            float* sp = scr + wv*SROW2 + ch*36;
            #pragma unroll
            for (int c = 0; c < 8; ++c) {
                float4 x = Mreg[c], y = Mreg[8+c];
                float px = rsum_hi(s0*x.x + s1*y.x);
                float py = rsum_hi(s0*x.y + s1*y.y);
                float pz = rsum_hi(s0*x.z + s1*y.z);
                float pw = rsum_hi(s0*x.w + s1*y.w);
                if (lane < 16) *(float4*)(sp + 4*c) = make_float4(px,py,pz,pw);
            }
        }
        __syncthreads();   // b8

        // ---- N: combine r over 16 waves (float4, 2 waves) ----
        if (tid < 128) {
            const int off = CIDX2(tid<<2);
            float4 r = make_float4(0.f,0.f,0.f,0.f);
            #pragma unroll
            for (int w = 0; w < 16; ++w) {
                float4 v = *(const float4*)&scr[w*SROW2 + off];
                r.x += v.x; r.y += v.y; r.z += v.z; r.w += v.w;
            }
            *(float4*)&r_S[tid<<2] = r;
        }
        __syncthreads();   // b9

        // ---- O: actor logits (one wave per logit, Wa in registers) ----
        {
            float acc = 0.f;
            #pragma unroll
            for (int j = 0; j < 8; ++j) acc += waR[j]*r_S[lane + (j<<6)];
            acc = wsum64(acc);
            if (lane == 0) logit_S[wv] = acc + ba_S[wv];
        }
        __syncthreads();   // b10

        // ---- P: actor softmax + output (16 lanes) ----
        if (tid < 16) {
            float lg = logit_S[tid];
            float mx = lg;
            mx = fmaxf(mx, __shfl_xor(mx,1)); mx = fmaxf(mx, __shfl_xor(mx,2));
            mx = fmaxf(mx, __shfl_xor(mx,4)); mx = fmaxf(mx, __shfl_xor(mx,8));
            float ex2 = __expf(lg - mx);
            float s = ex2;
            s += __shfl_xor(s,1); s += __shfl_xor(s,2);
            s += __shfl_xor(s,4); s += __shfl_xor(s,8);
            out[(size_t)(t*NB + n)*17 + tid] = ex2/s;
        }
    }
}

// ---------------- host launch ----------------
extern "C" void kernel_launch(void* const* d_in, const int* in_sizes, int n_in,
                              void* d_out, int out_size, void* d_ws, size_t ws_size,
                              hipStream_t stream) {
    const float* inp  = (const float*)d_in[0];
    const float* w_ih = (const float*)d_in[1];
    const float* w_hh = (const float*)d_in[2];
    const float* b_ih = (const float*)d_in[3];
    const float* b_hh = (const float*)d_in[4];
    const float* Wf   = (const float*)d_in[5];
    const float* bf   = (const float*)d_in[6];
    const float* Wa   = (const float*)d_in[7];
    const float* ba   = (const float*)d_in[8];
    const float* Wc   = (const float*)d_in[9];
    const float* bc   = (const float*)d_in[10];
    float* out = (float*)d_out;

    float* ws = (float*)d_ws;
    float* wihT   = ws;                       // 64*1536
    float* whhT   = ws + 98304;               // 512*1536
    float* h_all  = ws + 884736;              // 1024*512
    float* xi_all = ws + 1409024;             // 1024*3607
    float* hG     = ws + 5102592;             // 32*512 h exchange
    int*   flags  = (int*)(ws + 5119008);     // 32 counters

    static int dynset = 0;
    if (!dynset) {
        hipFuncSetAttribute(reinterpret_cast<const void*>(k_mem),
                            hipFuncAttributeMaxDynamicSharedMemorySize,
                            DYN_FLOATS*4);
        dynset = 1;
    }

    hipMemsetAsync(flags, 0, NB*sizeof(int), stream);

    dim3 tb(32, 8);
    k_transpose<<<dim3(48, 2),  tb, 0, stream>>>(w_ih, wihT, G3, DOBS);
    k_transpose<<<dim3(48, 16), tb, 0, stream>>>(w_hh, whhT, G3, HID);
    k_gru<<<NB*4, 384, 0, stream>>>(inp, wihT, whhT, b_ih, b_hh, h_all, hG, flags);
    k_xi<<<dim3(57, 8), 256, 0, stream>>>(h_all, Wf, bf, xi_all);
    k_val<<<TT*NB, 64, 0, stream>>>(h_all, Wc, bc, out);
    k_mem<<<NB, 1024, DYN_FLOATS*4, stream>>>(xi_all, Wa, ba, out);
}